// Round 1
// baseline (1106.491 us; speedup 1.0000x reference)
//
#include <hip/hip_runtime.h>
#include <stdint.h>

typedef __attribute__((ext_vector_type(8))) __bf16 bf16x8;
typedef __attribute__((ext_vector_type(4))) float f32x4;

#define DEV static __device__ __forceinline__

DEV unsigned short f2bf(float f) {
    unsigned int u = __float_as_uint(f);
    u = (u + 0x7fffu + ((u >> 16) & 1u)) >> 16;
    return (unsigned short)u;
}
DEV float bf2f(unsigned short h) { return __uint_as_float((unsigned int)h << 16); }

DEV void async_ld16(const void* g, void* l) {
    __builtin_amdgcn_global_load_lds(
        (const __attribute__((address_space(1))) void*)g,
        (__attribute__((address_space(3))) void*)l, 16, 0, 0);
}

DEV f32x4 mfma16(bf16x8 a, bf16x8 b, f32x4 c) {
    return __builtin_amdgcn_mfma_f32_16x16x32_bf16(a, b, c, 0, 0, 0);
}

// ---------------- weight transpose fp32[K][N] -> bf16[N][K] ----------------
__global__ __launch_bounds__(256) void wconv_kernel(
    const float* __restrict__ src, unsigned short* __restrict__ dst, int K, int N)
{
    __shared__ float tile[32][33];
    const int tx = threadIdx.x & 31;
    const int ty = threadIdx.x >> 5;
    const long nb = blockIdx.x;
    const long kb = blockIdx.y;
#pragma unroll
    for (int i = 0; i < 32; i += 8)
        tile[ty + i][tx] = src[(kb * 32 + ty + i) * N + nb * 32 + tx];
    __syncthreads();
#pragma unroll
    for (int i = 0; i < 32; i += 8)
        dst[(nb * 32 + ty + i) * K + kb * 32 + tx] = f2bf(tile[tx][ty + i]);
}

__global__ void pack_bias_kernel(const float* __restrict__ bq, const float* __restrict__ bk,
                                 const float* __restrict__ bv, float* __restrict__ o)
{
    int i = blockIdx.x * 256 + threadIdx.x;
    if (i < 1024) o[i] = bq[i];
    else if (i < 2048) o[i] = bk[i - 1024];
    else if (i < 3072) o[i] = bv[i - 2048];
}

// ---------------- LayerNorm: fp32 in -> bf16 out (wave per token, D=1024) ----
__global__ __launch_bounds__(256) void ln_kernel(
    const float* __restrict__ x, const float* __restrict__ scale,
    const float* __restrict__ bias, unsigned short* __restrict__ out)
{
    const int lane = threadIdx.x & 63;
    const int wave = threadIdx.x >> 6;
    const long tok = (long)blockIdx.x * 4 + wave;
    const float* xp = x + tok * 1024;
    float4 v[4];
    float sum = 0.f, sq = 0.f;
#pragma unroll
    for (int i = 0; i < 4; ++i) {
        v[i] = ((const float4*)xp)[i * 64 + lane];
        sum += v[i].x + v[i].y + v[i].z + v[i].w;
        sq += v[i].x * v[i].x + v[i].y * v[i].y + v[i].z * v[i].z + v[i].w * v[i].w;
    }
#pragma unroll
    for (int off = 1; off < 64; off <<= 1) {
        sum += __shfl_xor(sum, off);
        sq  += __shfl_xor(sq, off);
    }
    const float mu = sum * (1.f / 1024.f);
    const float var = sq * (1.f / 1024.f) - mu * mu;
    const float rs = rsqrtf(var + 1e-6f);
#pragma unroll
    for (int i = 0; i < 4; ++i) {
        const float4 sc = ((const float4*)scale)[i * 64 + lane];
        const float4 bi = ((const float4*)bias)[i * 64 + lane];
        ushort4 o;
        o.x = f2bf((v[i].x - mu) * rs * sc.x + bi.x);
        o.y = f2bf((v[i].y - mu) * rs * sc.y + bi.y);
        o.z = f2bf((v[i].z - mu) * rs * sc.z + bi.z);
        o.w = f2bf((v[i].w - mu) * rs * sc.w + bi.w);
        *(ushort4*)&out[tok * 1024 + (i * 64 + lane) * 4] = o;
    }
}

// ---------------- GEMM: C = A(MxK) * Bt(NxK)^T, bf16 MFMA, m97 structure ----
// EPI 0: +bias -> bf16 ; EPI 1: +bias,gelu -> bf16 ; EPI 2: +bias+resid -> f32
template <int EPI>
__global__ __launch_bounds__(256) void gemm_kernel(
    const unsigned short* __restrict__ A, const unsigned short* __restrict__ Bt,
    const float* __restrict__ bias, const float* __restrict__ resid,
    void* __restrict__ Cout, int M, int N, int K)
{
    __shared__ unsigned short As[4096];
    __shared__ unsigned short Bs[4096];
    const int tid = threadIdx.x;
    const int lane = tid & 63;
    const int wave = tid >> 6;
    const int wr = wave >> 1, wc = wave & 1;
    const long row0 = (long)blockIdx.y * 128;
    const long col0 = (long)blockIdx.x * 128;

    f32x4 acc[4][4];
#pragma unroll
    for (int i = 0; i < 4; ++i)
#pragma unroll
        for (int j = 0; j < 4; ++j) acc[i][j] = f32x4{0.f, 0.f, 0.f, 0.f};

    const unsigned short* Ag = A + (row0 + (tid >> 2)) * (long)K + (tid & 3) * 8;
    const unsigned short* Bg = Bt + (col0 + (tid >> 2)) * (long)K + (tid & 3) * 8;
    unsigned short* Asl = &As[tid * 8];
    unsigned short* Bsl = &Bs[tid * 8];
    const long Koff = 64l * K;

    const int lr = lane & 15;
    const int lk = (lane >> 4) * 8;

    for (int k0 = 0; k0 < K; k0 += 32) {
        async_ld16(Ag + k0, Asl);
        async_ld16(Ag + Koff + k0, Asl + 2048);
        async_ld16(Bg + k0, Bsl);
        async_ld16(Bg + Koff + k0, Bsl + 2048);
        __syncthreads();
        bf16x8 af[4], bfr[4];
#pragma unroll
        for (int m = 0; m < 4; ++m)
            af[m] = *(const bf16x8*)&As[(wr * 64 + m * 16 + lr) * 32 + lk];
#pragma unroll
        for (int n = 0; n < 4; ++n)
            bfr[n] = *(const bf16x8*)&Bs[(wc * 64 + n * 16 + lr) * 32 + lk];
#pragma unroll
        for (int m = 0; m < 4; ++m)
#pragma unroll
            for (int n = 0; n < 4; ++n)
                acc[m][n] = mfma16(af[m], bfr[n], acc[m][n]);
        __syncthreads();
    }

    const int r4 = (lane >> 4) * 4;
#pragma unroll
    for (int n = 0; n < 4; ++n) {
        const long c = col0 + wc * 64 + n * 16 + lr;
        const float bv = bias[c];
#pragma unroll
        for (int m = 0; m < 4; ++m) {
#pragma unroll
            for (int r = 0; r < 4; ++r) {
                const long rr = row0 + wr * 64 + m * 16 + r4 + r;
                float v = acc[m][n][r] + bv;
                if (EPI == 1) {
                    const float u = 0.7978845608028654f * (v + 0.044715f * v * v * v);
                    v = 0.5f * v * (1.0f + tanhf(u));
                }
                if (EPI == 2) {
                    v += resid[rr * N + c];
                    ((float*)Cout)[rr * N + c] = v;
                } else {
                    ((unsigned short*)Cout)[rr * N + c] = f2bf(v);
                }
            }
        }
    }
}

// ---------------- RoPE over q,k halves of qkv, position = t = (token/16)%128 --
__global__ __launch_bounds__(256) void rope_kernel(unsigned short* __restrict__ qkv)
{
    const long tid = (long)blockIdx.x * 256 + threadIdx.x; // 16,777,216 total
    const int d = (int)(tid & 31);
    const int h = (int)((tid >> 5) & 15);
    const int qk = (int)((tid >> 9) & 1);
    const long token = tid >> 10;
    const int t = (int)((token >> 4) & 127);
    unsigned short* p = qkv + token * 3072 + qk * 1024 + h * 64 + d;
    const float x1 = bf2f(p[0]);
    const float x2 = bf2f(p[32]);
    const float inv = __expf((float)d * -0.2878231366242557f); // 10000^(-d/32)
    const float f = (float)t * inv;
    float sn, cs;
    sincosf(f, &sn, &cs);
    p[0]  = f2bf(x1 * cs - x2 * sn);
    p[32] = f2bf(x2 * cs + x1 * sn);
}

// ---------------- temporal attention: block per (b,m,h), S=128, causal -------
__global__ __launch_bounds__(256) void attn_temporal(
    const unsigned short* __restrict__ qkv, unsigned short* __restrict__ out)
{
    const int bid = blockIdx.x;
    const int h = bid & 15;
    const int mm = (bid >> 4) & 15;
    const int b = bid >> 8;
    const int tid = threadIdx.x;
    const int lane = tid & 63;
    const int wave = tid >> 6;
    const int lr = lane & 15;
    const int lk = (lane >> 4) * 8;
    const int r4 = (lane >> 4) * 4;

    __shared__ __align__(16) unsigned short smemA[128 * 136]; // Ks then aliased Ps
    __shared__ __align__(16) unsigned short smemV[64 * 136];
    unsigned short (*Ks)[72] = (unsigned short (*)[72])smemA;
    unsigned short (*Ps)[136] = (unsigned short (*)[136])smemA;
    unsigned short (*Vt)[136] = (unsigned short (*)[136])smemV;

    const long tokbase = (long)b * 2048 + mm; // token(t) = tokbase + 16*t

#pragma unroll
    for (int i = 0; i < 4; ++i) { // K tile: 128 x 64, 8-elem chunks
        const int cc = tid + 256 * i;
        const int s = cc >> 3, part = cc & 7;
        const unsigned short* g = qkv + (tokbase + s * 16l) * 3072 + 1024 + h * 64 + part * 8;
        *(uint4*)&Ks[s][part * 8] = *(const uint4*)g;
    }
#pragma unroll
    for (int i = 0; i < 4; ++i) { // V tile transposed into Vt[d][s]
        const int cc = tid + 256 * i;
        const int s = cc >> 3, part = cc & 7;
        const unsigned short* g = qkv + (tokbase + s * 16l) * 3072 + 2048 + h * 64 + part * 8;
        union { uint4 u; unsigned short us[8]; } uu;
        uu.u = *(const uint4*)g;
#pragma unroll
        for (int j = 0; j < 8; ++j) Vt[part * 8 + j][s] = uu.us[j];
    }
    __syncthreads();

    bf16x8 qf[2][2]; // Q frags direct from global
#pragma unroll
    for (int rb = 0; rb < 2; ++rb)
#pragma unroll
        for (int ks = 0; ks < 2; ++ks) {
            const int t = wave * 32 + rb * 16 + lr;
            qf[rb][ks] = *(const bf16x8*)(qkv + (tokbase + t * 16l) * 3072 + h * 64 + ks * 32 + lk);
        }

    f32x4 sacc[2][8];
#pragma unroll
    for (int rb = 0; rb < 2; ++rb)
#pragma unroll
        for (int cb = 0; cb < 8; ++cb) sacc[rb][cb] = f32x4{0.f, 0.f, 0.f, 0.f};

#pragma unroll
    for (int cb = 0; cb < 8; ++cb)
#pragma unroll
        for (int ks = 0; ks < 2; ++ks) {
            const bf16x8 kf = *(const bf16x8*)&Ks[cb * 16 + lr][ks * 32 + lk];
            sacc[0][cb] = mfma16(qf[0][ks], kf, sacc[0][cb]);
            sacc[1][cb] = mfma16(qf[1][ks], kf, sacc[1][cb]);
        }

    float recip[2][4];
#pragma unroll
    for (int rb = 0; rb < 2; ++rb)
#pragma unroll
        for (int r = 0; r < 4; ++r) {
            const int trow = wave * 32 + rb * 16 + r4 + r;
            float mx = -1e30f;
#pragma unroll
            for (int cb = 0; cb < 8; ++cb) {
                const int s = cb * 16 + lr;
                const float v = (s <= trow) ? sacc[rb][cb][r] * 0.125f : -1e30f;
                sacc[rb][cb][r] = v;
                mx = fmaxf(mx, v);
            }
            mx = fmaxf(mx, __shfl_xor(mx, 1));
            mx = fmaxf(mx, __shfl_xor(mx, 2));
            mx = fmaxf(mx, __shfl_xor(mx, 4));
            mx = fmaxf(mx, __shfl_xor(mx, 8));
            float sum = 0.f;
#pragma unroll
            for (int cb = 0; cb < 8; ++cb) {
                const float e = __expf(sacc[rb][cb][r] - mx);
                sacc[rb][cb][r] = e;
                sum += e;
            }
            sum += __shfl_xor(sum, 1);
            sum += __shfl_xor(sum, 2);
            sum += __shfl_xor(sum, 4);
            sum += __shfl_xor(sum, 8);
            recip[rb][r] = 1.f / sum;
        }
    __syncthreads(); // all waves done reading Ks before overwriting with Ps

#pragma unroll
    for (int rb = 0; rb < 2; ++rb)
#pragma unroll
        for (int cb = 0; cb < 8; ++cb)
#pragma unroll
            for (int r = 0; r < 4; ++r)
                Ps[wave * 32 + rb * 16 + r4 + r][cb * 16 + lr] = f2bf(sacc[rb][cb][r]);
    __syncthreads();

    f32x4 oacc[2][4];
#pragma unroll
    for (int rb = 0; rb < 2; ++rb)
#pragma unroll
        for (int cb = 0; cb < 4; ++cb) oacc[rb][cb] = f32x4{0.f, 0.f, 0.f, 0.f};

#pragma unroll
    for (int ks = 0; ks < 4; ++ks) {
        bf16x8 pf[2];
        pf[0] = *(const bf16x8*)&Ps[wave * 32 + lr][ks * 32 + lk];
        pf[1] = *(const bf16x8*)&Ps[wave * 32 + 16 + lr][ks * 32 + lk];
#pragma unroll
        for (int cb = 0; cb < 4; ++cb) {
            const bf16x8 vf = *(const bf16x8*)&Vt[cb * 16 + lr][ks * 32 + lk];
            oacc[0][cb] = mfma16(pf[0], vf, oacc[0][cb]);
            oacc[1][cb] = mfma16(pf[1], vf, oacc[1][cb]);
        }
    }

#pragma unroll
    for (int rb = 0; rb < 2; ++rb)
#pragma unroll
        for (int cb = 0; cb < 4; ++cb)
#pragma unroll
            for (int r = 0; r < 4; ++r) {
                const int trow = wave * 32 + rb * 16 + r4 + r;
                out[(tokbase + trow * 16l) * 1024 + h * 64 + cb * 16 + lr] =
                    f2bf(oacc[rb][cb][r] * recip[rb][r]);
            }
}

// ---------------- modality attention: block per (b,t), S=16, 4 heads/wave ----
__global__ __launch_bounds__(256) void attn_modality(
    const unsigned short* __restrict__ qkv, unsigned short* __restrict__ out)
{
    const int tid = threadIdx.x;
    const int lane = tid & 63;
    const int wave = tid >> 6;
    const int lr = lane & 15;
    const int lk = (lane >> 4) * 8;
    const int r4 = (lane >> 4) * 4;
    const long base = (long)blockIdx.x * 16;

    __shared__ __align__(16) unsigned short smem[4][64 * 40 + 16 * 40]; // per-wave Vt + P
    unsigned short (*Vt)[40] = (unsigned short (*)[40]) & smem[wave][0];
    unsigned short (*Pl)[40] = (unsigned short (*)[40]) & smem[wave][64 * 40];

    // zero whole per-wave region once (zero-padding for K=16 -> 32)
    for (int i = lane; i < 400; i += 64)
        *(uint4*)&smem[wave][i * 8] = make_uint4(0u, 0u, 0u, 0u);

    for (int hi = 0; hi < 4; ++hi) {
        const int h = wave * 4 + hi;
#pragma unroll
        for (int i = 0; i < 2; ++i) { // V head tile 16x64 transposed
            const int cc = lane + 64 * i;
            const int s = cc >> 3, d0 = (cc & 7) * 8;
            union { uint4 u; unsigned short us[8]; } uu;
            uu.u = *(const uint4*)(qkv + (base + s) * 3072 + 2048 + h * 64 + d0);
#pragma unroll
            for (int j = 0; j < 8; ++j) Vt[d0 + j][s] = uu.us[j];
        }
        bf16x8 qf[2], kf[2];
#pragma unroll
        for (int ks = 0; ks < 2; ++ks) {
            qf[ks] = *(const bf16x8*)(qkv + (base + lr) * 3072 + h * 64 + ks * 32 + lk);
            kf[ks] = *(const bf16x8*)(qkv + (base + lr) * 3072 + 1024 + h * 64 + ks * 32 + lk);
        }
        f32x4 sv = f32x4{0.f, 0.f, 0.f, 0.f};
        sv = mfma16(qf[0], kf[0], sv);
        sv = mfma16(qf[1], kf[1], sv);

        float recip[4], pe[4];
#pragma unroll
        for (int r = 0; r < 4; ++r) {
            const float v = sv[r] * 0.125f;
            float mx = v;
            mx = fmaxf(mx, __shfl_xor(mx, 1));
            mx = fmaxf(mx, __shfl_xor(mx, 2));
            mx = fmaxf(mx, __shfl_xor(mx, 4));
            mx = fmaxf(mx, __shfl_xor(mx, 8));
            const float e = __expf(v - mx);
            float sum = e;
            sum += __shfl_xor(sum, 1);
            sum += __shfl_xor(sum, 2);
            sum += __shfl_xor(sum, 4);
            sum += __shfl_xor(sum, 8);
            recip[r] = 1.f / sum;
            pe[r] = e;
        }
#pragma unroll
        for (int r = 0; r < 4; ++r) Pl[r4 + r][lr] = f2bf(pe[r]);

        const bf16x8 pf = *(const bf16x8*)&Pl[lr][lk];
#pragma unroll
        for (int cb = 0; cb < 4; ++cb) {
            const bf16x8 vf = *(const bf16x8*)&Vt[cb * 16 + lr][lk];
            f32x4 o = f32x4{0.f, 0.f, 0.f, 0.f};
            o = mfma16(pf, vf, o);
#pragma unroll
            for (int r = 0; r < 4; ++r)
                out[(base + r4 + r) * 1024 + h * 64 + cb * 16 + lr] = f2bf(o[r] * recip[r]);
        }
    }
}

// -----------------------------------------------------------------------------
extern "C" void kernel_launch(void* const* d_in, const int* in_sizes, int n_in,
                              void* d_out, int out_size, void* d_ws, size_t ws_size,
                              hipStream_t stream)
{
    (void)in_sizes; (void)n_in; (void)out_size;
    const float* x    = (const float*)d_in[0];
    const float* ln1s = (const float*)d_in[1];
    const float* ln1b = (const float*)d_in[2];
    const float* tWq  = (const float*)d_in[3];
    const float* tbq  = (const float*)d_in[4];
    const float* tWk  = (const float*)d_in[5];
    const float* tbk  = (const float*)d_in[6];
    const float* tWv  = (const float*)d_in[7];
    const float* tbv  = (const float*)d_in[8];
    const float* tWo  = (const float*)d_in[9];
    const float* tbo  = (const float*)d_in[10];
    const float* ln2s = (const float*)d_in[11];
    const float* ln2b = (const float*)d_in[12];
    const float* mWq  = (const float*)d_in[13];
    const float* mbq  = (const float*)d_in[14];
    const float* mWk  = (const float*)d_in[15];
    const float* mbk  = (const float*)d_in[16];
    const float* mWv  = (const float*)d_in[17];
    const float* mbv  = (const float*)d_in[18];
    const float* mWo  = (const float*)d_in[19];
    const float* mbo  = (const float*)d_in[20];
    const float* ln3s = (const float*)d_in[21];
    const float* ln3b = (const float*)d_in[22];
    const float* W1   = (const float*)d_in[23];
    const float* b1   = (const float*)d_in[24];
    const float* W2   = (const float*)d_in[25];
    const float* b2   = (const float*)d_in[26];

    if (ws_size < 201351168ull) return; // need ~192 MiB scratch

    char* ws = (char*)d_ws;
    unsigned short* Wt_tqkv = (unsigned short*)(ws + 0);
    unsigned short* Wt_to   = (unsigned short*)(ws + 6291456);
    unsigned short* Wt_mqkv = (unsigned short*)(ws + 8388608);
    unsigned short* Wt_mo   = (unsigned short*)(ws + 14680064);
    unsigned short* Wt1     = (unsigned short*)(ws + 16777216);
    unsigned short* Wt2     = (unsigned short*)(ws + 25165824);
    float* bias_t           = (float*)(ws + 33554432);
    float* bias_m           = (float*)(ws + 33566720);
    unsigned short* act     = (unsigned short*)(ws + 33579008); // LN out / attn out (33.5MB)
    unsigned short* qkv     = (unsigned short*)(ws + 67133440); // 100.7MB, reused as MLP hidden
    unsigned short* hidden  = qkv;
    float* xout = (float*)d_out; // fp32 residual stream lives in d_out

    dim3 blk(256);

    // weight conversion (per call; deterministic, ~25us)
    wconv_kernel<<<dim3(32, 32), blk, 0, stream>>>(tWq, Wt_tqkv, 1024, 1024);
    wconv_kernel<<<dim3(32, 32), blk, 0, stream>>>(tWk, Wt_tqkv + 1024 * 1024, 1024, 1024);
    wconv_kernel<<<dim3(32, 32), blk, 0, stream>>>(tWv, Wt_tqkv + 2048 * 1024, 1024, 1024);
    wconv_kernel<<<dim3(32, 32), blk, 0, stream>>>(tWo, Wt_to, 1024, 1024);
    wconv_kernel<<<dim3(32, 32), blk, 0, stream>>>(mWq, Wt_mqkv, 1024, 1024);
    wconv_kernel<<<dim3(32, 32), blk, 0, stream>>>(mWk, Wt_mqkv + 1024 * 1024, 1024, 1024);
    wconv_kernel<<<dim3(32, 32), blk, 0, stream>>>(mWv, Wt_mqkv + 2048 * 1024, 1024, 1024);
    wconv_kernel<<<dim3(32, 32), blk, 0, stream>>>(mWo, Wt_mo, 1024, 1024);
    wconv_kernel<<<dim3(128, 32), blk, 0, stream>>>(W1, Wt1, 1024, 4096);
    wconv_kernel<<<dim3(32, 128), blk, 0, stream>>>(W2, Wt2, 4096, 1024);
    pack_bias_kernel<<<12, blk, 0, stream>>>(tbq, tbk, tbv, bias_t);
    pack_bias_kernel<<<12, blk, 0, stream>>>(mbq, mbk, mbv, bias_m);

    // 1. LN1
    ln_kernel<<<4096, blk, 0, stream>>>(x, ln1s, ln1b, act);
    // 2. temporal QKV
    gemm_kernel<0><<<dim3(24, 128), blk, 0, stream>>>(act, Wt_tqkv, bias_t, nullptr, qkv, 16384, 3072, 1024);
    // 3. RoPE on q,k
    rope_kernel<<<65536, blk, 0, stream>>>(qkv);
    // 4. temporal attention (causal over T=128)
    attn_temporal<<<2048, blk, 0, stream>>>(qkv, act);
    // 5. out-proj + residual(x) -> xout (fp32)
    gemm_kernel<2><<<dim3(8, 128), blk, 0, stream>>>(act, Wt_to, tbo, x, xout, 16384, 1024, 1024);
    // 6. LN2
    ln_kernel<<<4096, blk, 0, stream>>>(xout, ln2s, ln2b, act);
    // 7. modality QKV
    gemm_kernel<0><<<dim3(24, 128), blk, 0, stream>>>(act, Wt_mqkv, bias_m, nullptr, qkv, 16384, 3072, 1024);
    // 8. modality attention (S=16, no mask, no rope)
    attn_modality<<<1024, blk, 0, stream>>>(qkv, act);
    // 9. out-proj + residual -> xout
    gemm_kernel<2><<<dim3(8, 128), blk, 0, stream>>>(act, Wt_mo, mbo, xout, xout, 16384, 1024, 1024);
    // 10. LN3
    ln_kernel<<<4096, blk, 0, stream>>>(xout, ln3s, ln3b, act);
    // 11. MLP up + GELU
    gemm_kernel<1><<<dim3(32, 128), blk, 0, stream>>>(act, Wt1, b1, nullptr, hidden, 16384, 4096, 1024);
    // 12. MLP down + residual -> xout
    gemm_kernel<2><<<dim3(8, 128), blk, 0, stream>>>(hidden, Wt2, b2, xout, xout, 16384, 1024, 4096);
}

// Round 2
// 1106.229 us; speedup vs baseline: 1.0002x; 1.0002x over previous
//
#include <hip/hip_runtime.h>
#include <stdint.h>

typedef __attribute__((ext_vector_type(8))) __bf16 bf16x8;
typedef __attribute__((ext_vector_type(4))) float f32x4;

#define DEV static __device__ __forceinline__

DEV unsigned short f2bf(float f) {
    unsigned int u = __float_as_uint(f);
    u = (u + 0x7fffu + ((u >> 16) & 1u)) >> 16;
    return (unsigned short)u;
}
DEV float bf2f(unsigned short h) { return __uint_as_float((unsigned int)h << 16); }

DEV void async_ld16(const void* g, void* l) {
    __builtin_amdgcn_global_load_lds(
        (const __attribute__((address_space(1))) void*)g,
        (__attribute__((address_space(3))) void*)l, 16, 0, 0);
}

DEV f32x4 mfma16(bf16x8 a, bf16x8 b, f32x4 c) {
    return __builtin_amdgcn_mfma_f32_16x16x32_bf16(a, b, c, 0, 0, 0);
}

// ---------------- weight transpose fp32[K][N] -> bf16[N][K] ----------------
__global__ __launch_bounds__(256) void wconv_kernel(
    const float* __restrict__ src, unsigned short* __restrict__ dst, int K, int N)
{
    __shared__ float tile[32][33];
    const int tx = threadIdx.x & 31;
    const int ty = threadIdx.x >> 5;
    const long nb = blockIdx.x;
    const long kb = blockIdx.y;
#pragma unroll
    for (int i = 0; i < 32; i += 8)
        tile[ty + i][tx] = src[(kb * 32 + ty + i) * N + nb * 32 + tx];
    __syncthreads();
#pragma unroll
    for (int i = 0; i < 32; i += 8)
        dst[(nb * 32 + ty + i) * K + kb * 32 + tx] = f2bf(tile[tx][ty + i]);
}

__global__ void pack_bias_kernel(const float* __restrict__ bq, const float* __restrict__ bk,
                                 const float* __restrict__ bv, float* __restrict__ o)
{
    int i = blockIdx.x * 256 + threadIdx.x;
    if (i < 1024) o[i] = bq[i];
    else if (i < 2048) o[i] = bk[i - 1024];
    else if (i < 3072) o[i] = bv[i - 2048];
}

// ---------------- LayerNorm: fp32 in -> bf16 out (wave per token, D=1024) ----
__global__ __launch_bounds__(256) void ln_kernel(
    const float* __restrict__ x, const float* __restrict__ scale,
    const float* __restrict__ bias, unsigned short* __restrict__ out)
{
    const int lane = threadIdx.x & 63;
    const int wave = threadIdx.x >> 6;
    const long tok = (long)blockIdx.x * 4 + wave;
    const float* xp = x + tok * 1024;
    float4 v[4];
    float sum = 0.f, sq = 0.f;
#pragma unroll
    for (int i = 0; i < 4; ++i) {
        v[i] = ((const float4*)xp)[i * 64 + lane];
        sum += v[i].x + v[i].y + v[i].z + v[i].w;
        sq += v[i].x * v[i].x + v[i].y * v[i].y + v[i].z * v[i].z + v[i].w * v[i].w;
    }
#pragma unroll
    for (int off = 1; off < 64; off <<= 1) {
        sum += __shfl_xor(sum, off);
        sq  += __shfl_xor(sq, off);
    }
    const float mu = sum * (1.f / 1024.f);
    const float var = sq * (1.f / 1024.f) - mu * mu;
    const float rs = rsqrtf(var + 1e-6f);
#pragma unroll
    for (int i = 0; i < 4; ++i) {
        const float4 sc = ((const float4*)scale)[i * 64 + lane];
        const float4 bi = ((const float4*)bias)[i * 64 + lane];
        ushort4 o;
        o.x = f2bf((v[i].x - mu) * rs * sc.x + bi.x);
        o.y = f2bf((v[i].y - mu) * rs * sc.y + bi.y);
        o.z = f2bf((v[i].z - mu) * rs * sc.z + bi.z);
        o.w = f2bf((v[i].w - mu) * rs * sc.w + bi.w);
        *(ushort4*)&out[tok * 1024 + (i * 64 + lane) * 4] = o;
    }
}

// ---------------- GEMM: C = A(MxK) * Bt(NxK)^T, bf16 MFMA, m97 structure ----
// EPI 0: +bias -> bf16 ; EPI 1: +bias,gelu -> bf16 ; EPI 2: +bias+resid -> f32
template <int EPI>
__global__ __launch_bounds__(256) void gemm_kernel(
    const unsigned short* __restrict__ A, const unsigned short* __restrict__ Bt,
    const float* __restrict__ bias, const float* __restrict__ resid,
    void* __restrict__ Cout, int M, int N, int K)
{
    __shared__ unsigned short As[4096];
    __shared__ unsigned short Bs[4096];
    const int tid = threadIdx.x;
    const int lane = tid & 63;
    const int wave = tid >> 6;
    const int wr = wave >> 1, wc = wave & 1;
    const long row0 = (long)blockIdx.y * 128;
    const long col0 = (long)blockIdx.x * 128;

    f32x4 acc[4][4];
#pragma unroll
    for (int i = 0; i < 4; ++i)
#pragma unroll
        for (int j = 0; j < 4; ++j) acc[i][j] = f32x4{0.f, 0.f, 0.f, 0.f};

    const unsigned short* Ag = A + (row0 + (tid >> 2)) * (long)K + (tid & 3) * 8;
    const unsigned short* Bg = Bt + (col0 + (tid >> 2)) * (long)K + (tid & 3) * 8;
    unsigned short* Asl = &As[tid * 8];
    unsigned short* Bsl = &Bs[tid * 8];
    const long Koff = 64l * K;

    const int lr = lane & 15;
    const int lk = (lane >> 4) * 8;

    for (int k0 = 0; k0 < K; k0 += 32) {
        async_ld16(Ag + k0, Asl);
        async_ld16(Ag + Koff + k0, Asl + 2048);
        async_ld16(Bg + k0, Bsl);
        async_ld16(Bg + Koff + k0, Bsl + 2048);
        __syncthreads();
        bf16x8 af[4], bfr[4];
#pragma unroll
        for (int m = 0; m < 4; ++m)
            af[m] = *(const bf16x8*)&As[(wr * 64 + m * 16 + lr) * 32 + lk];
#pragma unroll
        for (int n = 0; n < 4; ++n)
            bfr[n] = *(const bf16x8*)&Bs[(wc * 64 + n * 16 + lr) * 32 + lk];
#pragma unroll
        for (int m = 0; m < 4; ++m)
#pragma unroll
            for (int n = 0; n < 4; ++n)
                acc[m][n] = mfma16(af[m], bfr[n], acc[m][n]);
        __syncthreads();
    }

    const int r4 = (lane >> 4) * 4;
#pragma unroll
    for (int n = 0; n < 4; ++n) {
        const long c = col0 + wc * 64 + n * 16 + lr;
        const float bv = bias[c];
#pragma unroll
        for (int m = 0; m < 4; ++m) {
#pragma unroll
            for (int r = 0; r < 4; ++r) {
                const long rr = row0 + wr * 64 + m * 16 + r4 + r;
                float v = acc[m][n][r] + bv;
                if (EPI == 1) {
                    const float u = 0.7978845608028654f * (v + 0.044715f * v * v * v);
                    v = 0.5f * v * (1.0f + tanhf(u));
                }
                if (EPI == 2) {
                    v += resid[rr * N + c];
                    ((float*)Cout)[rr * N + c] = v;
                } else {
                    ((unsigned short*)Cout)[rr * N + c] = f2bf(v);
                }
            }
        }
    }
}

// ---------------- RoPE over q,k halves of qkv, position = t = (token/16)%128 --
__global__ __launch_bounds__(256) void rope_kernel(unsigned short* __restrict__ qkv)
{
    const long tid = (long)blockIdx.x * 256 + threadIdx.x; // 16,777,216 total
    const int d = (int)(tid & 31);
    const int h = (int)((tid >> 5) & 15);
    const int qk = (int)((tid >> 9) & 1);
    const long token = tid >> 10;
    const int t = (int)((token >> 4) & 127);
    unsigned short* p = qkv + token * 3072 + qk * 1024 + h * 64 + d;
    const float x1 = bf2f(p[0]);
    const float x2 = bf2f(p[32]);
    const float inv = __expf((float)d * -0.2878231366242557f); // 10000^(-d/32)
    const float f = (float)t * inv;
    float sn, cs;
    sincosf(f, &sn, &cs);
    p[0]  = f2bf(x1 * cs - x2 * sn);
    p[32] = f2bf(x2 * cs + x1 * sn);
}

// ---------------- temporal attention: block per (b,m,h), S=128, causal -------
__global__ __launch_bounds__(256) void attn_temporal(
    const unsigned short* __restrict__ qkv, unsigned short* __restrict__ out)
{
    const int bid = blockIdx.x;
    const int h = bid & 15;
    const int mm = (bid >> 4) & 15;
    const int b = bid >> 8;
    const int tid = threadIdx.x;
    const int lane = tid & 63;
    const int wave = tid >> 6;
    const int lr = lane & 15;
    const int lk = (lane >> 4) * 8;
    const int r4 = (lane >> 4) * 4;

    __shared__ __align__(16) unsigned short smemA[128 * 136]; // Ks then aliased Ps
    __shared__ __align__(16) unsigned short smemV[64 * 136];
    unsigned short (*Ks)[72] = (unsigned short (*)[72])smemA;
    unsigned short (*Ps)[136] = (unsigned short (*)[136])smemA;
    unsigned short (*Vt)[136] = (unsigned short (*)[136])smemV;

    const long tokbase = (long)b * 2048 + mm; // token(t) = tokbase + 16*t

#pragma unroll
    for (int i = 0; i < 4; ++i) { // K tile: 128 x 64, 8-elem chunks
        const int cc = tid + 256 * i;
        const int s = cc >> 3, part = cc & 7;
        const unsigned short* g = qkv + (tokbase + s * 16l) * 3072 + 1024 + h * 64 + part * 8;
        *(uint4*)&Ks[s][part * 8] = *(const uint4*)g;
    }
#pragma unroll
    for (int i = 0; i < 4; ++i) { // V tile transposed into Vt[d][s]
        const int cc = tid + 256 * i;
        const int s = cc >> 3, part = cc & 7;
        const unsigned short* g = qkv + (tokbase + s * 16l) * 3072 + 2048 + h * 64 + part * 8;
        union { uint4 u; unsigned short us[8]; } uu;
        uu.u = *(const uint4*)g;
#pragma unroll
        for (int j = 0; j < 8; ++j) Vt[part * 8 + j][s] = uu.us[j];
    }
    __syncthreads();

    bf16x8 qf[2][2]; // Q frags direct from global
#pragma unroll
    for (int rb = 0; rb < 2; ++rb)
#pragma unroll
        for (int ks = 0; ks < 2; ++ks) {
            const int t = wave * 32 + rb * 16 + lr;
            qf[rb][ks] = *(const bf16x8*)(qkv + (tokbase + t * 16l) * 3072 + h * 64 + ks * 32 + lk);
        }

    f32x4 sacc[2][8];
#pragma unroll
    for (int rb = 0; rb < 2; ++rb)
#pragma unroll
        for (int cb = 0; cb < 8; ++cb) sacc[rb][cb] = f32x4{0.f, 0.f, 0.f, 0.f};

#pragma unroll
    for (int cb = 0; cb < 8; ++cb)
#pragma unroll
        for (int ks = 0; ks < 2; ++ks) {
            const bf16x8 kf = *(const bf16x8*)&Ks[cb * 16 + lr][ks * 32 + lk];
            sacc[0][cb] = mfma16(qf[0][ks], kf, sacc[0][cb]);
            sacc[1][cb] = mfma16(qf[1][ks], kf, sacc[1][cb]);
        }

    float recip[2][4];
#pragma unroll
    for (int rb = 0; rb < 2; ++rb)
#pragma unroll
        for (int r = 0; r < 4; ++r) {
            const int trow = wave * 32 + rb * 16 + r4 + r;
            float mx = -1e30f;
#pragma unroll
            for (int cb = 0; cb < 8; ++cb) {
                const int s = cb * 16 + lr;
                const float v = (s <= trow) ? sacc[rb][cb][r] * 0.125f : -1e30f;
                sacc[rb][cb][r] = v;
                mx = fmaxf(mx, v);
            }
            mx = fmaxf(mx, __shfl_xor(mx, 1));
            mx = fmaxf(mx, __shfl_xor(mx, 2));
            mx = fmaxf(mx, __shfl_xor(mx, 4));
            mx = fmaxf(mx, __shfl_xor(mx, 8));
            float sum = 0.f;
#pragma unroll
            for (int cb = 0; cb < 8; ++cb) {
                const float e = __expf(sacc[rb][cb][r] - mx);
                sacc[rb][cb][r] = e;
                sum += e;
            }
            sum += __shfl_xor(sum, 1);
            sum += __shfl_xor(sum, 2);
            sum += __shfl_xor(sum, 4);
            sum += __shfl_xor(sum, 8);
            recip[rb][r] = 1.f / sum;
        }
    __syncthreads(); // all waves done reading Ks before overwriting with Ps

#pragma unroll
    for (int rb = 0; rb < 2; ++rb)
#pragma unroll
        for (int cb = 0; cb < 8; ++cb)
#pragma unroll
            for (int r = 0; r < 4; ++r)
                Ps[wave * 32 + rb * 16 + r4 + r][cb * 16 + lr] = f2bf(sacc[rb][cb][r]);
    __syncthreads();

    f32x4 oacc[2][4];
#pragma unroll
    for (int rb = 0; rb < 2; ++rb)
#pragma unroll
        for (int cb = 0; cb < 4; ++cb) oacc[rb][cb] = f32x4{0.f, 0.f, 0.f, 0.f};

#pragma unroll
    for (int ks = 0; ks < 4; ++ks) {
        bf16x8 pf[2];
        pf[0] = *(const bf16x8*)&Ps[wave * 32 + lr][ks * 32 + lk];
        pf[1] = *(const bf16x8*)&Ps[wave * 32 + 16 + lr][ks * 32 + lk];
#pragma unroll
        for (int cb = 0; cb < 4; ++cb) {
            const bf16x8 vf = *(const bf16x8*)&Vt[cb * 16 + lr][ks * 32 + lk];
            oacc[0][cb] = mfma16(pf[0], vf, oacc[0][cb]);
            oacc[1][cb] = mfma16(pf[1], vf, oacc[1][cb]);
        }
    }

#pragma unroll
    for (int rb = 0; rb < 2; ++rb)
#pragma unroll
        for (int cb = 0; cb < 4; ++cb)
#pragma unroll
            for (int r = 0; r < 4; ++r) {
                const int trow = wave * 32 + rb * 16 + r4 + r;
                out[(tokbase + trow * 16l) * 1024 + h * 64 + cb * 16 + lr] =
                    f2bf(oacc[rb][cb][r] * recip[rb][r]);
            }
}

// ---------------- modality attention: block per (b,t), S=16, 4 heads/wave ----
__global__ __launch_bounds__(256) void attn_modality(
    const unsigned short* __restrict__ qkv, unsigned short* __restrict__ out)
{
    const int tid = threadIdx.x;
    const int lane = tid & 63;
    const int wave = tid >> 6;
    const int lr = lane & 15;
    const int lk = (lane >> 4) * 8;
    const int r4 = (lane >> 4) * 4;
    const long base = (long)blockIdx.x * 16;

    __shared__ __align__(16) unsigned short smem[4][64 * 40 + 16 * 40]; // per-wave Vt + P
    unsigned short (*Vt)[40] = (unsigned short (*)[40]) & smem[wave][0];
    unsigned short (*Pl)[40] = (unsigned short (*)[40]) & smem[wave][64 * 40];

    // zero whole per-wave region once (zero-padding for K=16 -> 32)
    for (int i = lane; i < 400; i += 64)
        *(uint4*)&smem[wave][i * 8] = make_uint4(0u, 0u, 0u, 0u);

    for (int hi = 0; hi < 4; ++hi) {
        const int h = wave * 4 + hi;
#pragma unroll
        for (int i = 0; i < 2; ++i) { // V head tile 16x64 transposed
            const int cc = lane + 64 * i;
            const int s = cc >> 3, d0 = (cc & 7) * 8;
            union { uint4 u; unsigned short us[8]; } uu;
            uu.u = *(const uint4*)(qkv + (base + s) * 3072 + 2048 + h * 64 + d0);
#pragma unroll
            for (int j = 0; j < 8; ++j) Vt[d0 + j][s] = uu.us[j];
        }
        bf16x8 qf[2], kf[2];
#pragma unroll
        for (int ks = 0; ks < 2; ++ks) {
            qf[ks] = *(const bf16x8*)(qkv + (base + lr) * 3072 + h * 64 + ks * 32 + lk);
            kf[ks] = *(const bf16x8*)(qkv + (base + lr) * 3072 + 1024 + h * 64 + ks * 32 + lk);
        }
        f32x4 sv = f32x4{0.f, 0.f, 0.f, 0.f};
        sv = mfma16(qf[0], kf[0], sv);
        sv = mfma16(qf[1], kf[1], sv);

        float recip[4], pe[4];
#pragma unroll
        for (int r = 0; r < 4; ++r) {
            const float v = sv[r] * 0.125f;
            float mx = v;
            mx = fmaxf(mx, __shfl_xor(mx, 1));
            mx = fmaxf(mx, __shfl_xor(mx, 2));
            mx = fmaxf(mx, __shfl_xor(mx, 4));
            mx = fmaxf(mx, __shfl_xor(mx, 8));
            const float e = __expf(v - mx);
            float sum = e;
            sum += __shfl_xor(sum, 1);
            sum += __shfl_xor(sum, 2);
            sum += __shfl_xor(sum, 4);
            sum += __shfl_xor(sum, 8);
            recip[r] = 1.f / sum;
            pe[r] = e;
        }
#pragma unroll
        for (int r = 0; r < 4; ++r) Pl[r4 + r][lr] = f2bf(pe[r]);

        const bf16x8 pf = *(const bf16x8*)&Pl[lr][lk];
#pragma unroll
        for (int cb = 0; cb < 4; ++cb) {
            const bf16x8 vf = *(const bf16x8*)&Vt[cb * 16 + lr][lk];
            f32x4 o = f32x4{0.f, 0.f, 0.f, 0.f};
            o = mfma16(pf, vf, o);
#pragma unroll
            for (int r = 0; r < 4; ++r)
                out[(base + r4 + r) * 1024 + h * 64 + cb * 16 + lr] = f2bf(o[r] * recip[r]);
        }
    }
}

// -----------------------------------------------------------------------------
extern "C" void kernel_launch(void* const* d_in, const int* in_sizes, int n_in,
                              void* d_out, int out_size, void* d_ws, size_t ws_size,
                              hipStream_t stream)
{
    (void)in_sizes; (void)n_in; (void)out_size;
    const float* x    = (const float*)d_in[0];
    const float* ln1s = (const float*)d_in[1];
    const float* ln1b = (const float*)d_in[2];
    const float* tWq  = (const float*)d_in[3];
    const float* tbq  = (const float*)d_in[4];
    const float* tWk  = (const float*)d_in[5];
    const float* tbk  = (const float*)d_in[6];
    const float* tWv  = (const float*)d_in[7];
    const float* tbv  = (const float*)d_in[8];
    const float* tWo  = (const float*)d_in[9];
    const float* tbo  = (const float*)d_in[10];
    const float* ln2s = (const float*)d_in[11];
    const float* ln2b = (const float*)d_in[12];
    const float* mWq  = (const float*)d_in[13];
    const float* mbq  = (const float*)d_in[14];
    const float* mWk  = (const float*)d_in[15];
    const float* mbk  = (const float*)d_in[16];
    const float* mWv  = (const float*)d_in[17];
    const float* mbv  = (const float*)d_in[18];
    const float* mWo  = (const float*)d_in[19];
    const float* mbo  = (const float*)d_in[20];
    const float* ln3s = (const float*)d_in[21];
    const float* ln3b = (const float*)d_in[22];
    const float* W1   = (const float*)d_in[23];
    const float* b1   = (const float*)d_in[24];
    const float* W2   = (const float*)d_in[25];
    const float* b2   = (const float*)d_in[26];

    if (ws_size < 201351168ull) return; // need ~192 MiB scratch

    char* ws = (char*)d_ws;
    unsigned short* Wt_tqkv = (unsigned short*)(ws + 0);
    unsigned short* Wt_to   = (unsigned short*)(ws + 6291456);
    unsigned short* Wt_mqkv = (unsigned short*)(ws + 8388608);
    unsigned short* Wt_mo   = (unsigned short*)(ws + 14680064);
    unsigned short* Wt1     = (unsigned short*)(ws + 16777216);
    unsigned short* Wt2     = (unsigned short*)(ws + 25165824);
    float* bias_t           = (float*)(ws + 33554432);
    float* bias_m           = (float*)(ws + 33566720);
    unsigned short* act     = (unsigned short*)(ws + 33579008); // LN out / attn out (33.5MB)
    unsigned short* qkv     = (unsigned short*)(ws + 67133440); // 100.7MB, reused as MLP hidden
    unsigned short* hidden  = qkv;
    float* xout = (float*)d_out; // fp32 residual stream lives in d_out

    dim3 blk(256);

    // weight conversion (per call; deterministic, ~25us)
    wconv_kernel<<<dim3(32, 32), blk, 0, stream>>>(tWq, Wt_tqkv, 1024, 1024);
    wconv_kernel<<<dim3(32, 32), blk, 0, stream>>>(tWk, Wt_tqkv + 1024 * 1024, 1024, 1024);
    wconv_kernel<<<dim3(32, 32), blk, 0, stream>>>(tWv, Wt_tqkv + 2048 * 1024, 1024, 1024);
    wconv_kernel<<<dim3(32, 32), blk, 0, stream>>>(tWo, Wt_to, 1024, 1024);
    wconv_kernel<<<dim3(32, 32), blk, 0, stream>>>(mWq, Wt_mqkv, 1024, 1024);
    wconv_kernel<<<dim3(32, 32), blk, 0, stream>>>(mWk, Wt_mqkv + 1024 * 1024, 1024, 1024);
    wconv_kernel<<<dim3(32, 32), blk, 0, stream>>>(mWv, Wt_mqkv + 2048 * 1024, 1024, 1024);
    wconv_kernel<<<dim3(32, 32), blk, 0, stream>>>(mWo, Wt_mo, 1024, 1024);
    wconv_kernel<<<dim3(128, 32), blk, 0, stream>>>(W1, Wt1, 1024, 4096);
    wconv_kernel<<<dim3(32, 128), blk, 0, stream>>>(W2, Wt2, 4096, 1024);
    pack_bias_kernel<<<12, blk, 0, stream>>>(tbq, tbk, tbv, bias_t);
    pack_bias_kernel<<<12, blk, 0, stream>>>(mbq, mbk, mbv, bias_m);

    // 1. LN1
    ln_kernel<<<4096, blk, 0, stream>>>(x, ln1s, ln1b, act);
    // 2. temporal QKV
    gemm_kernel<0><<<dim3(24, 128), blk, 0, stream>>>(act, Wt_tqkv, bias_t, nullptr, qkv, 16384, 3072, 1024);
    // 3. RoPE on q,k
    rope_kernel<<<65536, blk, 0, stream>>>(qkv);
    // 4. temporal attention (causal over T=128)
    attn_temporal<<<2048, blk, 0, stream>>>(qkv, act);
    // 5. out-proj + residual(x) -> xout (fp32)
    gemm_kernel<2><<<dim3(8, 128), blk, 0, stream>>>(act, Wt_to, tbo, x, xout, 16384, 1024, 1024);
    // 6. LN2
    ln_kernel<<<4096, blk, 0, stream>>>(xout, ln2s, ln2b, act);
    // 7. modality QKV
    gemm_kernel<0><<<dim3(24, 128), blk, 0, stream>>>(act, Wt_mqkv, bias_m, nullptr, qkv, 16384, 3072, 1024);
    // 8. modality attention (S=16, no mask, no rope)
    attn_modality<<<1024, blk, 0, stream>>>(qkv, act);
    // 9. out-proj + residual -> xout
    gemm_kernel<2><<<dim3(8, 128), blk, 0, stream>>>(act, Wt_mo, mbo, xout, xout, 16384, 1024, 1024);
    // 10. LN3
    ln_kernel<<<4096, blk, 0, stream>>>(xout, ln3s, ln3b, act);
    // 11. MLP up + GELU
    gemm_kernel<1><<<dim3(32, 128), blk, 0, stream>>>(act, Wt1, b1, nullptr, hidden, 16384, 4096, 1024);
    // 12. MLP down + residual -> xout
    gemm_kernel<2><<<dim3(8, 128), blk, 0, stream>>>(hidden, Wt2, b2, xout, xout, 16384, 1024, 4096);
}

// Round 3
// 803.458 us; speedup vs baseline: 1.3772x; 1.3768x over previous
//
#include <hip/hip_runtime.h>
#include <stdint.h>

typedef __attribute__((ext_vector_type(8))) __bf16 bf16x8;
typedef __attribute__((ext_vector_type(4))) float f32x4;

#define DEV static __device__ __forceinline__

DEV unsigned short f2bf(float f) {
    unsigned int u = __float_as_uint(f);
    u = (u + 0x7fffu + ((u >> 16) & 1u)) >> 16;
    return (unsigned short)u;
}
DEV float bf2f(unsigned short h) { return __uint_as_float((unsigned int)h << 16); }

DEV void async_ld16(const void* g, void* l) {
    __builtin_amdgcn_global_load_lds(
        (const __attribute__((address_space(1))) void*)g,
        (__attribute__((address_space(3))) void*)l, 16, 0, 0);
}

DEV f32x4 mfma16(bf16x8 a, bf16x8 b, f32x4 c) {
    return __builtin_amdgcn_mfma_f32_16x16x32_bf16(a, b, c, 0, 0, 0);
}

DEV float gelu_f(float v) {
    float u = 0.7978845608028654f * (v + 0.044715f * v * v * v);
    u = fminf(fmaxf(u, -9.f), 9.f);
    const float e = __expf(2.f * u);
    const float th = (e - 1.f) / (e + 1.f);
    return 0.5f * v * (1.0f + th);
}

// ---------------- weight transpose fp32[K][N] -> bf16[N][K] ----------------
__global__ __launch_bounds__(256) void wconv_kernel(
    const float* __restrict__ src, unsigned short* __restrict__ dst, int K, int N)
{
    __shared__ float tile[32][33];
    const int tx = threadIdx.x & 31;
    const int ty = threadIdx.x >> 5;
    const long nb = blockIdx.x;
    const long kb = blockIdx.y;
#pragma unroll
    for (int i = 0; i < 32; i += 8)
        tile[ty + i][tx] = src[(kb * 32 + ty + i) * N + nb * 32 + tx];
    __syncthreads();
#pragma unroll
    for (int i = 0; i < 32; i += 8)
        dst[(nb * 32 + ty + i) * K + kb * 32 + tx] = f2bf(tile[tx][ty + i]);
}

__global__ void pack_bias_kernel(const float* __restrict__ bq, const float* __restrict__ bk,
                                 const float* __restrict__ bv, float* __restrict__ o)
{
    int i = blockIdx.x * 256 + threadIdx.x;
    if (i < 1024) o[i] = bq[i];
    else if (i < 2048) o[i] = bk[i - 1024];
    else if (i < 3072) o[i] = bv[i - 2048];
}

// ---------------- LayerNorm: fp32 in -> bf16 out (wave per token, D=1024) ----
__global__ __launch_bounds__(256) void ln_kernel(
    const float* __restrict__ x, const float* __restrict__ scale,
    const float* __restrict__ bias, unsigned short* __restrict__ out)
{
    const int lane = threadIdx.x & 63;
    const int wave = threadIdx.x >> 6;
    const long tok = (long)blockIdx.x * 4 + wave;
    const float* xp = x + tok * 1024;
    float4 v[4];
    float sum = 0.f, sq = 0.f;
#pragma unroll
    for (int i = 0; i < 4; ++i) {
        v[i] = ((const float4*)xp)[i * 64 + lane];
        sum += v[i].x + v[i].y + v[i].z + v[i].w;
        sq += v[i].x * v[i].x + v[i].y * v[i].y + v[i].z * v[i].z + v[i].w * v[i].w;
    }
#pragma unroll
    for (int off = 1; off < 64; off <<= 1) {
        sum += __shfl_xor(sum, off);
        sq  += __shfl_xor(sq, off);
    }
    const float mu = sum * (1.f / 1024.f);
    const float var = sq * (1.f / 1024.f) - mu * mu;
    const float rs = rsqrtf(var + 1e-6f);
#pragma unroll
    for (int i = 0; i < 4; ++i) {
        const float4 sc = ((const float4*)scale)[i * 64 + lane];
        const float4 bi = ((const float4*)bias)[i * 64 + lane];
        ushort4 o;
        o.x = f2bf((v[i].x - mu) * rs * sc.x + bi.x);
        o.y = f2bf((v[i].y - mu) * rs * sc.y + bi.y);
        o.z = f2bf((v[i].z - mu) * rs * sc.z + bi.z);
        o.w = f2bf((v[i].w - mu) * rs * sc.w + bi.w);
        *(ushort4*)&out[tok * 1024 + (i * 64 + lane) * 4] = o;
    }
}

// ---------------- GEMM 256x256 tile, BK=64, 8 waves, counted-vmcnt pipeline --
// C = A(MxK) * Bt(NxK)^T.  EPI 0: +bias -> bf16 ; 1: +bias,gelu -> bf16 ;
// 2: +bias+resid -> f32.  T1 XCD swizzle, T2 LDS swizzle, T4 vmcnt(8), T5 prio.
template <int EPI>
__global__ __launch_bounds__(512, 2) void gemm256_kernel(
    const unsigned short* __restrict__ A, const unsigned short* __restrict__ Bt,
    const float* __restrict__ bias, const float* __restrict__ resid,
    void* __restrict__ Cout, int M, int N, int K, int nbx)
{
    __shared__ __align__(16) unsigned short lds[2][2][16384]; // [buf][A/B][256*64]
    const int tid = threadIdx.x;
    const int lane = tid & 63;
    const int wave = tid >> 6;
    const int wr = wave >> 2;   // 0..1  (M half)
    const int wc = wave & 3;    // 0..3  (N quarter)
    const int lr = lane & 15;
    const int hi = lane >> 4;   // 0..3

    // T1: bijective XCD swizzle (grid always a multiple of 8)
    const int nwg = gridDim.x;
    const int cpx = nwg >> 3;
    int bid = blockIdx.x;
    bid = (bid & 7) * cpx + (bid >> 3);
    const int bx = bid % nbx, by = bid / nbx;
    const long row0 = (long)by * 256;
    const long col0 = (long)bx * 256;

    const int NT = K >> 6;

    // staging: thread covers LDS linear (i*8192 + tid*16) bytes of each op-tile
    // LDS dest is linear; global source is pre-swizzled (chunk ^= row&7)
    const int srow = tid >> 3;                      // 0..63 (row within 64-row group)
    const int scL = (tid & 7) ^ (srow & 7);         // logical k-chunk for this slot
    const unsigned short* gA = A + (row0 + srow) * (long)K + scL * 8;
    const unsigned short* gB = Bt + (col0 + srow) * (long)K + scL * 8;

    auto stage = [&](int kt, int buf) {
        const long ko = (long)kt * 64;
#pragma unroll
        for (int i = 0; i < 4; ++i)
            async_ld16(gA + i * 64 * (long)K + ko, &lds[buf][0][i * 4096 + tid * 8]);
#pragma unroll
        for (int i = 0; i < 4; ++i)
            async_ld16(gB + i * 64 * (long)K + ko, &lds[buf][1][i * 4096 + tid * 8]);
    };

    // compute-side swizzled k-chunk byte offsets (row&7 == lr&7 for all frags)
    int cOff[2];
#pragma unroll
    for (int ks = 0; ks < 2; ++ks)
        cOff[ks] = (((ks << 2) | hi) ^ (lr & 7)) << 4;

    f32x4 acc[8][4];
#pragma unroll
    for (int i = 0; i < 8; ++i)
#pragma unroll
        for (int j = 0; j < 4; ++j) acc[i][j] = f32x4{0.f, 0.f, 0.f, 0.f};

    stage(0, 0);
    if (NT > 1) stage(1, 1);

    for (int kt = 0; kt < NT; ++kt) {
        const int cur = kt & 1;
        if (kt == NT - 1) { asm volatile("s_waitcnt vmcnt(0)" ::: "memory"); }
        else              { asm volatile("s_waitcnt vmcnt(8)" ::: "memory"); }
        __builtin_amdgcn_sched_barrier(0);
        __builtin_amdgcn_s_barrier();   // whole tile resident for every wave

        const char* baseA = (const char*)&lds[cur][0][0];
        const char* baseB = (const char*)&lds[cur][1][0];

        bf16x8 bfrag[4][2], afrag[4][2];
#pragma unroll
        for (int n = 0; n < 4; ++n)
#pragma unroll
            for (int ks = 0; ks < 2; ++ks)
                bfrag[n][ks] = *(const bf16x8*)(baseB + (wc * 64 + n * 16 + lr) * 128 + cOff[ks]);
#pragma unroll
        for (int mm = 0; mm < 4; ++mm)
#pragma unroll
            for (int ks = 0; ks < 2; ++ks)
                afrag[mm][ks] = *(const bf16x8*)(baseA + (wr * 128 + mm * 16 + lr) * 128 + cOff[ks]);

        __builtin_amdgcn_s_setprio(1);
#pragma unroll
        for (int ks = 0; ks < 2; ++ks)
#pragma unroll
            for (int mm = 0; mm < 4; ++mm)
#pragma unroll
                for (int n = 0; n < 4; ++n)
                    acc[mm][n] = mfma16(afrag[mm][ks], bfrag[n][ks], acc[mm][n]);
        __builtin_amdgcn_s_setprio(0);

#pragma unroll
        for (int mm = 0; mm < 4; ++mm)
#pragma unroll
            for (int ks = 0; ks < 2; ++ks)
                afrag[mm][ks] = *(const bf16x8*)(baseA + (wr * 128 + 64 + mm * 16 + lr) * 128 + cOff[ks]);

        __builtin_amdgcn_s_setprio(1);
#pragma unroll
        for (int ks = 0; ks < 2; ++ks)
#pragma unroll
            for (int mm = 0; mm < 4; ++mm)
#pragma unroll
                for (int n = 0; n < 4; ++n)
                    acc[4 + mm][n] = mfma16(afrag[mm][ks], bfrag[n][ks], acc[4 + mm][n]);
        __builtin_amdgcn_s_setprio(0);

        __builtin_amdgcn_s_barrier();   // all waves done reading buf[cur]
        if (kt + 2 < NT) stage(kt + 2, cur);
    }

    // ---- epilogue (LDS-staged, coalesced stores) ----
    float bcol[4];
#pragma unroll
    for (int n = 0; n < 4; ++n) bcol[n] = bias[col0 + wc * 64 + n * 16 + lr];

    if (EPI == 2) {
        float (*eF)[256] = (float (*)[256])&lds[0][0][0]; // 128 x 256 f32 = 128 KB
        float* co = (float*)Cout;
#pragma unroll
        for (int half = 0; half < 2; ++half) {
            if (wr == half) {
#pragma unroll
                for (int m = 0; m < 8; ++m)
#pragma unroll
                    for (int n = 0; n < 4; ++n)
#pragma unroll
                        for (int j = 0; j < 4; ++j)
                            eF[m * 16 + hi * 4 + j][wc * 64 + n * 16 + lr] = acc[m][n][j] + bcol[n];
            }
            __syncthreads();
#pragma unroll
            for (int it = 0; it < 16; ++it) {
                const int idx = it * 512 + tid;
                const int row = idx >> 6;
                const int ch = (idx & 63) * 4;
                const long g = row0 + half * 128 + row;
                float4 v = *(const float4*)&eF[row][ch];
                const float4 rv = *(const float4*)&resid[g * N + col0 + ch];
                v.x += rv.x; v.y += rv.y; v.z += rv.z; v.w += rv.w;
                *(float4*)&co[g * N + col0 + ch] = v;
            }
            __syncthreads();
        }
    } else {
        unsigned short (*eT)[256] = (unsigned short (*)[256])&lds[0][0][0]; // 256x256 bf16
        unsigned short* co = (unsigned short*)Cout;
#pragma unroll
        for (int m = 0; m < 8; ++m)
#pragma unroll
            for (int n = 0; n < 4; ++n)
#pragma unroll
                for (int j = 0; j < 4; ++j) {
                    float v = acc[m][n][j] + bcol[n];
                    if (EPI == 1) v = gelu_f(v);
                    eT[wr * 128 + m * 16 + hi * 4 + j][wc * 64 + n * 16 + lr] = f2bf(v);
                }
        __syncthreads();
#pragma unroll
        for (int it = 0; it < 16; ++it) {
            const int idx = it * 512 + tid;
            const int row = idx >> 5;
            const int ch = (idx & 31) * 8;
            *(uint4*)&co[(row0 + row) * N + col0 + ch] = *(const uint4*)&eT[row][ch];
        }
    }
}

// ---------------- RoPE over q,k halves of qkv, position = t = (token/16)%128 --
__global__ __launch_bounds__(256) void rope_kernel(unsigned short* __restrict__ qkv)
{
    const long tid = (long)blockIdx.x * 256 + threadIdx.x; // 16,777,216 total
    const int d = (int)(tid & 31);
    const int h = (int)((tid >> 5) & 15);
    const int qk = (int)((tid >> 9) & 1);
    const long token = tid >> 10;
    const int t = (int)((token >> 4) & 127);
    unsigned short* p = qkv + token * 3072 + qk * 1024 + h * 64 + d;
    const float x1 = bf2f(p[0]);
    const float x2 = bf2f(p[32]);
    const float inv = __expf((float)d * -0.2878231366242557f); // 10000^(-d/32)
    const float f = (float)t * inv;
    float sn, cs;
    sincosf(f, &sn, &cs);
    p[0]  = f2bf(x1 * cs - x2 * sn);
    p[32] = f2bf(x2 * cs + x1 * sn);
}

// ---------------- temporal attention: block per (b,m,h), S=128, causal -------
__global__ __launch_bounds__(256) void attn_temporal(
    const unsigned short* __restrict__ qkv, unsigned short* __restrict__ out)
{
    const int bid = blockIdx.x;
    const int h = bid & 15;
    const int mm = (bid >> 4) & 15;
    const int b = bid >> 8;
    const int tid = threadIdx.x;
    const int lane = tid & 63;
    const int wave = tid >> 6;
    const int lr = lane & 15;
    const int lk = (lane >> 4) * 8;
    const int r4 = (lane >> 4) * 4;

    __shared__ __align__(16) unsigned short smemA[128 * 136]; // Ks then aliased Ps
    __shared__ __align__(16) unsigned short smemV[64 * 136];
    unsigned short (*Ks)[72] = (unsigned short (*)[72])smemA;
    unsigned short (*Ps)[136] = (unsigned short (*)[136])smemA;
    unsigned short (*Vt)[136] = (unsigned short (*)[136])smemV;

    const long tokbase = (long)b * 2048 + mm; // token(t) = tokbase + 16*t

#pragma unroll
    for (int i = 0; i < 4; ++i) { // K tile: 128 x 64, 8-elem chunks
        const int cc = tid + 256 * i;
        const int s = cc >> 3, part = cc & 7;
        const unsigned short* g = qkv + (tokbase + s * 16l) * 3072 + 1024 + h * 64 + part * 8;
        *(uint4*)&Ks[s][part * 8] = *(const uint4*)g;
    }
#pragma unroll
    for (int i = 0; i < 4; ++i) { // V tile transposed into Vt[d][s]
        const int cc = tid + 256 * i;
        const int s = cc >> 3, part = cc & 7;
        const unsigned short* g = qkv + (tokbase + s * 16l) * 3072 + 2048 + h * 64 + part * 8;
        union { uint4 u; unsigned short us[8]; } uu;
        uu.u = *(const uint4*)g;
#pragma unroll
        for (int j = 0; j < 8; ++j) Vt[part * 8 + j][s] = uu.us[j];
    }
    __syncthreads();

    bf16x8 qf[2][2]; // Q frags direct from global
#pragma unroll
    for (int rb = 0; rb < 2; ++rb)
#pragma unroll
        for (int ks = 0; ks < 2; ++ks) {
            const int t = wave * 32 + rb * 16 + lr;
            qf[rb][ks] = *(const bf16x8*)(qkv + (tokbase + t * 16l) * 3072 + h * 64 + ks * 32 + lk);
        }

    f32x4 sacc[2][8];
#pragma unroll
    for (int rb = 0; rb < 2; ++rb)
#pragma unroll
        for (int cb = 0; cb < 8; ++cb) sacc[rb][cb] = f32x4{0.f, 0.f, 0.f, 0.f};

#pragma unroll
    for (int cb = 0; cb < 8; ++cb)
#pragma unroll
        for (int ks = 0; ks < 2; ++ks) {
            const bf16x8 kf = *(const bf16x8*)&Ks[cb * 16 + lr][ks * 32 + lk];
            sacc[0][cb] = mfma16(qf[0][ks], kf, sacc[0][cb]);
            sacc[1][cb] = mfma16(qf[1][ks], kf, sacc[1][cb]);
        }

    float recip[2][4];
#pragma unroll
    for (int rb = 0; rb < 2; ++rb)
#pragma unroll
        for (int r = 0; r < 4; ++r) {
            const int trow = wave * 32 + rb * 16 + r4 + r;
            float mx = -1e30f;
#pragma unroll
            for (int cb = 0; cb < 8; ++cb) {
                const int s = cb * 16 + lr;
                const float v = (s <= trow) ? sacc[rb][cb][r] * 0.125f : -1e30f;
                sacc[rb][cb][r] = v;
                mx = fmaxf(mx, v);
            }
            mx = fmaxf(mx, __shfl_xor(mx, 1));
            mx = fmaxf(mx, __shfl_xor(mx, 2));
            mx = fmaxf(mx, __shfl_xor(mx, 4));
            mx = fmaxf(mx, __shfl_xor(mx, 8));
            float sum = 0.f;
#pragma unroll
            for (int cb = 0; cb < 8; ++cb) {
                const float e = __expf(sacc[rb][cb][r] - mx);
                sacc[rb][cb][r] = e;
                sum += e;
            }
            sum += __shfl_xor(sum, 1);
            sum += __shfl_xor(sum, 2);
            sum += __shfl_xor(sum, 4);
            sum += __shfl_xor(sum, 8);
            recip[rb][r] = 1.f / sum;
        }
    __syncthreads(); // all waves done reading Ks before overwriting with Ps

#pragma unroll
    for (int rb = 0; rb < 2; ++rb)
#pragma unroll
        for (int cb = 0; cb < 8; ++cb)
#pragma unroll
            for (int r = 0; r < 4; ++r)
                Ps[wave * 32 + rb * 16 + r4 + r][cb * 16 + lr] = f2bf(sacc[rb][cb][r]);
    __syncthreads();

    f32x4 oacc[2][4];
#pragma unroll
    for (int rb = 0; rb < 2; ++rb)
#pragma unroll
        for (int cb = 0; cb < 4; ++cb) oacc[rb][cb] = f32x4{0.f, 0.f, 0.f, 0.f};

#pragma unroll
    for (int ks = 0; ks < 4; ++ks) {
        bf16x8 pf[2];
        pf[0] = *(const bf16x8*)&Ps[wave * 32 + lr][ks * 32 + lk];
        pf[1] = *(const bf16x8*)&Ps[wave * 32 + 16 + lr][ks * 32 + lk];
#pragma unroll
        for (int cb = 0; cb < 4; ++cb) {
            const bf16x8 vf = *(const bf16x8*)&Vt[cb * 16 + lr][ks * 32 + lk];
            oacc[0][cb] = mfma16(pf[0], vf, oacc[0][cb]);
            oacc[1][cb] = mfma16(pf[1], vf, oacc[1][cb]);
        }
    }

#pragma unroll
    for (int rb = 0; rb < 2; ++rb)
#pragma unroll
        for (int cb = 0; cb < 4; ++cb)
#pragma unroll
            for (int r = 0; r < 4; ++r) {
                const int trow = wave * 32 + rb * 16 + r4 + r;
                out[(tokbase + trow * 16l) * 1024 + h * 64 + cb * 16 + lr] =
                    f2bf(oacc[rb][cb][r] * recip[rb][r]);
            }
}

// ---------------- modality attention: block per (b,t), S=16, 4 heads/wave ----
__global__ __launch_bounds__(256) void attn_modality(
    const unsigned short* __restrict__ qkv, unsigned short* __restrict__ out)
{
    const int tid = threadIdx.x;
    const int lane = tid & 63;
    const int wave = tid >> 6;
    const int lr = lane & 15;
    const int lk = (lane >> 4) * 8;
    const int r4 = (lane >> 4) * 4;
    const long base = (long)blockIdx.x * 16;

    __shared__ __align__(16) unsigned short smem[4][64 * 40 + 16 * 40]; // per-wave Vt + P
    unsigned short (*Vt)[40] = (unsigned short (*)[40]) & smem[wave][0];
    unsigned short (*Pl)[40] = (unsigned short (*)[40]) & smem[wave][64 * 40];

    // zero whole per-wave region once (zero-padding for K=16 -> 32)
    for (int i = lane; i < 400; i += 64)
        *(uint4*)&smem[wave][i * 8] = make_uint4(0u, 0u, 0u, 0u);

    for (int hi = 0; hi < 4; ++hi) {
        const int h = wave * 4 + hi;
#pragma unroll
        for (int i = 0; i < 2; ++i) { // V head tile 16x64 transposed
            const int cc = lane + 64 * i;
            const int s = cc >> 3, d0 = (cc & 7) * 8;
            union { uint4 u; unsigned short us[8]; } uu;
            uu.u = *(const uint4*)(qkv + (base + s) * 3072 + 2048 + h * 64 + d0);
#pragma unroll
            for (int j = 0; j < 8; ++j) Vt[d0 + j][s] = uu.us[j];
        }
        bf16x8 qf[2], kf[2];
#pragma unroll
        for (int ks = 0; ks < 2; ++ks) {
            qf[ks] = *(const bf16x8*)(qkv + (base + lr) * 3072 + h * 64 + ks * 32 + lk);
            kf[ks] = *(const bf16x8*)(qkv + (base + lr) * 3072 + 1024 + h * 64 + ks * 32 + lk);
        }
        f32x4 sv = f32x4{0.f, 0.f, 0.f, 0.f};
        sv = mfma16(qf[0], kf[0], sv);
        sv = mfma16(qf[1], kf[1], sv);

        float recip[4], pe[4];
#pragma unroll
        for (int r = 0; r < 4; ++r) {
            const float v = sv[r] * 0.125f;
            float mx = v;
            mx = fmaxf(mx, __shfl_xor(mx, 1));
            mx = fmaxf(mx, __shfl_xor(mx, 2));
            mx = fmaxf(mx, __shfl_xor(mx, 4));
            mx = fmaxf(mx, __shfl_xor(mx, 8));
            const float e = __expf(v - mx);
            float sum = e;
            sum += __shfl_xor(sum, 1);
            sum += __shfl_xor(sum, 2);
            sum += __shfl_xor(sum, 4);
            sum += __shfl_xor(sum, 8);
            recip[r] = 1.f / sum;
            pe[r] = e;
        }
#pragma unroll
        for (int r = 0; r < 4; ++r) Pl[r4 + r][lr] = f2bf(pe[r]);

        const bf16x8 pf = *(const bf16x8*)&Pl[lr][lk];
#pragma unroll
        for (int cb = 0; cb < 4; ++cb) {
            const bf16x8 vf = *(const bf16x8*)&Vt[cb * 16 + lr][lk];
            f32x4 o = f32x4{0.f, 0.f, 0.f, 0.f};
            o = mfma16(pf, vf, o);
#pragma unroll
            for (int r = 0; r < 4; ++r)
                out[(base + r4 + r) * 1024 + h * 64 + cb * 16 + lr] = f2bf(o[r] * recip[r]);
        }
    }
}

// -----------------------------------------------------------------------------
extern "C" void kernel_launch(void* const* d_in, const int* in_sizes, int n_in,
                              void* d_out, int out_size, void* d_ws, size_t ws_size,
                              hipStream_t stream)
{
    (void)in_sizes; (void)n_in; (void)out_size;
    const float* x    = (const float*)d_in[0];
    const float* ln1s = (const float*)d_in[1];
    const float* ln1b = (const float*)d_in[2];
    const float* tWq  = (const float*)d_in[3];
    const float* tbq  = (const float*)d_in[4];
    const float* tWk  = (const float*)d_in[5];
    const float* tbk  = (const float*)d_in[6];
    const float* tWv  = (const float*)d_in[7];
    const float* tbv  = (const float*)d_in[8];
    const float* tWo  = (const float*)d_in[9];
    const float* tbo  = (const float*)d_in[10];
    const float* ln2s = (const float*)d_in[11];
    const float* ln2b = (const float*)d_in[12];
    const float* mWq  = (const float*)d_in[13];
    const float* mbq  = (const float*)d_in[14];
    const float* mWk  = (const float*)d_in[15];
    const float* mbk  = (const float*)d_in[16];
    const float* mWv  = (const float*)d_in[17];
    const float* mbv  = (const float*)d_in[18];
    const float* mWo  = (const float*)d_in[19];
    const float* mbo  = (const float*)d_in[20];
    const float* ln3s = (const float*)d_in[21];
    const float* ln3b = (const float*)d_in[22];
    const float* W1   = (const float*)d_in[23];
    const float* b1   = (const float*)d_in[24];
    const float* W2   = (const float*)d_in[25];
    const float* b2   = (const float*)d_in[26];

    if (ws_size < 201351168ull) return; // need ~192 MiB scratch

    char* ws = (char*)d_ws;
    unsigned short* Wt_tqkv = (unsigned short*)(ws + 0);
    unsigned short* Wt_to   = (unsigned short*)(ws + 6291456);
    unsigned short* Wt_mqkv = (unsigned short*)(ws + 8388608);
    unsigned short* Wt_mo   = (unsigned short*)(ws + 14680064);
    unsigned short* Wt1     = (unsigned short*)(ws + 16777216);
    unsigned short* Wt2     = (unsigned short*)(ws + 25165824);
    float* bias_t           = (float*)(ws + 33554432);
    float* bias_m           = (float*)(ws + 33566720);
    unsigned short* act     = (unsigned short*)(ws + 33579008); // LN out / attn out (33.5MB)
    unsigned short* qkv     = (unsigned short*)(ws + 67133440); // 100.7MB, reused as MLP hidden
    unsigned short* hidden  = qkv;
    float* xout = (float*)d_out; // fp32 residual stream lives in d_out

    dim3 blk(256);
    dim3 blk5(512);

    // weight conversion (per call; deterministic, ~25us)
    wconv_kernel<<<dim3(32, 32), blk, 0, stream>>>(tWq, Wt_tqkv, 1024, 1024);
    wconv_kernel<<<dim3(32, 32), blk, 0, stream>>>(tWk, Wt_tqkv + 1024 * 1024, 1024, 1024);
    wconv_kernel<<<dim3(32, 32), blk, 0, stream>>>(tWv, Wt_tqkv + 2048 * 1024, 1024, 1024);
    wconv_kernel<<<dim3(32, 32), blk, 0, stream>>>(tWo, Wt_to, 1024, 1024);
    wconv_kernel<<<dim3(32, 32), blk, 0, stream>>>(mWq, Wt_mqkv, 1024, 1024);
    wconv_kernel<<<dim3(32, 32), blk, 0, stream>>>(mWk, Wt_mqkv + 1024 * 1024, 1024, 1024);
    wconv_kernel<<<dim3(32, 32), blk, 0, stream>>>(mWv, Wt_mqkv + 2048 * 1024, 1024, 1024);
    wconv_kernel<<<dim3(32, 32), blk, 0, stream>>>(mWo, Wt_mo, 1024, 1024);
    wconv_kernel<<<dim3(128, 32), blk, 0, stream>>>(W1, Wt1, 1024, 4096);
    wconv_kernel<<<dim3(32, 128), blk, 0, stream>>>(W2, Wt2, 4096, 1024);
    pack_bias_kernel<<<12, blk, 0, stream>>>(tbq, tbk, tbv, bias_t);
    pack_bias_kernel<<<12, blk, 0, stream>>>(mbq, mbk, mbv, bias_m);

    // 1. LN1
    ln_kernel<<<4096, blk, 0, stream>>>(x, ln1s, ln1b, act);
    // 2. temporal QKV  (M=16384, N=3072, K=1024) -> grid 64*12=768
    gemm256_kernel<0><<<768, blk5, 0, stream>>>(act, Wt_tqkv, bias_t, nullptr, qkv, 16384, 3072, 1024, 12);
    // 3. RoPE on q,k
    rope_kernel<<<65536, blk, 0, stream>>>(qkv);
    // 4. temporal attention (causal over T=128)
    attn_temporal<<<2048, blk, 0, stream>>>(qkv, act);
    // 5. out-proj + residual(x) -> xout (fp32)   N=1024 -> grid 64*4=256
    gemm256_kernel<2><<<256, blk5, 0, stream>>>(act, Wt_to, tbo, x, xout, 16384, 1024, 1024, 4);
    // 6. LN2
    ln_kernel<<<4096, blk, 0, stream>>>(xout, ln2s, ln2b, act);
    // 7. modality QKV
    gemm256_kernel<0><<<768, blk5, 0, stream>>>(act, Wt_mqkv, bias_m, nullptr, qkv, 16384, 3072, 1024, 12);
    // 8. modality attention (S=16, no mask, no rope)
    attn_modality<<<1024, blk, 0, stream>>>(qkv, act);
    // 9. out-proj + residual -> xout
    gemm256_kernel<2><<<256, blk5, 0, stream>>>(act, Wt_mo, mbo, xout, xout, 16384, 1024, 1024, 4);
    // 10. LN3
    ln_kernel<<<4096, blk, 0, stream>>>(xout, ln3s, ln3b, act);
    // 11. MLP up + GELU  (N=4096) -> grid 64*16=1024
    gemm256_kernel<1><<<1024, blk5, 0, stream>>>(act, Wt1, b1, nullptr, hidden, 16384, 4096, 1024, 16);
    // 12. MLP down + residual -> xout  (K=4096)
    gemm256_kernel<2><<<256, blk5, 0, stream>>>(hidden, Wt2, b2, xout, xout, 16384, 1024, 4096, 4);
}

// Round 4
// 755.924 us; speedup vs baseline: 1.4638x; 1.0629x over previous
//
#include <hip/hip_runtime.h>
#include <stdint.h>

typedef __attribute__((ext_vector_type(8))) __bf16 bf16x8;
typedef __attribute__((ext_vector_type(4))) float f32x4;

#define DEV static __device__ __forceinline__

DEV unsigned short f2bf(float f) {
    unsigned int u = __float_as_uint(f);
    u = (u + 0x7fffu + ((u >> 16) & 1u)) >> 16;
    return (unsigned short)u;
}
DEV float bf2f(unsigned short h) { return __uint_as_float((unsigned int)h << 16); }

DEV void async_ld16(const void* g, void* l) {
    __builtin_amdgcn_global_load_lds(
        (const __attribute__((address_space(1))) void*)g,
        (__attribute__((address_space(3))) void*)l, 16, 0, 0);
}

DEV f32x4 mfma16(bf16x8 a, bf16x8 b, f32x4 c) {
    return __builtin_amdgcn_mfma_f32_16x16x32_bf16(a, b, c, 0, 0, 0);
}

DEV float gelu_f(float v) {
    float u = 0.7978845608028654f * (v + 0.044715f * v * v * v);
    u = fminf(fmaxf(u, -9.f), 9.f);
    const float e = __expf(2.f * u);
    const float th = (e - 1.f) / (e + 1.f);
    return 0.5f * v * (1.0f + th);
}

// ---------------- weight transpose fp32[K][N] -> bf16[N][K] ----------------
__global__ __launch_bounds__(256) void wconv_kernel(
    const float* __restrict__ src, unsigned short* __restrict__ dst, int K, int N)
{
    __shared__ float tile[32][33];
    const int tx = threadIdx.x & 31;
    const int ty = threadIdx.x >> 5;
    const long nb = blockIdx.x;
    const long kb = blockIdx.y;
#pragma unroll
    for (int i = 0; i < 32; i += 8)
        tile[ty + i][tx] = src[(kb * 32 + ty + i) * N + nb * 32 + tx];
    __syncthreads();
#pragma unroll
    for (int i = 0; i < 32; i += 8)
        dst[(nb * 32 + ty + i) * K + kb * 32 + tx] = f2bf(tile[tx][ty + i]);
}

__global__ void pack_bias_kernel(const float* __restrict__ bq, const float* __restrict__ bk,
                                 const float* __restrict__ bv, float* __restrict__ o)
{
    int i = blockIdx.x * 256 + threadIdx.x;
    if (i < 1024) o[i] = bq[i];
    else if (i < 2048) o[i] = bk[i - 1024];
    else if (i < 3072) o[i] = bv[i - 2048];
}

// ---------------- LayerNorm: fp32 in -> bf16 out (wave per token, D=1024) ----
__global__ __launch_bounds__(256) void ln_kernel(
    const float* __restrict__ x, const float* __restrict__ scale,
    const float* __restrict__ bias, unsigned short* __restrict__ out)
{
    const int lane = threadIdx.x & 63;
    const int wave = threadIdx.x >> 6;
    const long tok = (long)blockIdx.x * 4 + wave;
    const float* xp = x + tok * 1024;
    float4 v[4];
    float sum = 0.f, sq = 0.f;
#pragma unroll
    for (int i = 0; i < 4; ++i) {
        v[i] = ((const float4*)xp)[i * 64 + lane];
        sum += v[i].x + v[i].y + v[i].z + v[i].w;
        sq += v[i].x * v[i].x + v[i].y * v[i].y + v[i].z * v[i].z + v[i].w * v[i].w;
    }
#pragma unroll
    for (int off = 1; off < 64; off <<= 1) {
        sum += __shfl_xor(sum, off);
        sq  += __shfl_xor(sq, off);
    }
    const float mu = sum * (1.f / 1024.f);
    const float var = sq * (1.f / 1024.f) - mu * mu;
    const float rs = rsqrtf(var + 1e-6f);
#pragma unroll
    for (int i = 0; i < 4; ++i) {
        const float4 sc = ((const float4*)scale)[i * 64 + lane];
        const float4 bi = ((const float4*)bias)[i * 64 + lane];
        ushort4 o;
        o.x = f2bf((v[i].x - mu) * rs * sc.x + bi.x);
        o.y = f2bf((v[i].y - mu) * rs * sc.y + bi.y);
        o.z = f2bf((v[i].z - mu) * rs * sc.z + bi.z);
        o.w = f2bf((v[i].w - mu) * rs * sc.w + bi.w);
        *(ushort4*)&out[tok * 1024 + (i * 64 + lane) * 4] = o;
    }
}

// ---------------- GEMM 256x256, BK=64, 8 waves, 4-phase schedule -------------
// C = A(MxK) * Bt(NxK)^T. Phases = per-wave C-quadrants (m-half x n-half).
// A halves keyed by row bit6, B halves by col bit5 -> each phase reads exactly
// one A-half + one B-half. Staging: 1 half-tile/phase of tile t+1, counted
// vmcnt(4) at p1/p2/p3 (2 half-tiles allowed in flight), no drain in loop.
// EPI 0: +bias -> bf16 (opt. fused RoPE); 1: +bias,gelu -> bf16 ; 2: +bias+resid -> f32.
template <int EPI, bool ROPE>
__global__ __launch_bounds__(512, 2) void gemm256_kernel(
    const unsigned short* __restrict__ A, const unsigned short* __restrict__ Bt,
    const float* __restrict__ bias, const float* __restrict__ resid,
    void* __restrict__ Cout, int M, int N, int K, int nbx)
{
    __shared__ __align__(16) unsigned short lds[2][2][2][8192]; // [buf][A/B][half][128x64]
    const int tid = threadIdx.x;
    const int lane = tid & 63;
    const int wave = tid >> 6;
    const int wr = wave >> 2;   // 0..1  (M half, 128 rows)
    const int wc = wave & 3;    // 0..3  (N quarter, 64 cols)
    const int lr = lane & 15;
    const int hi = lane >> 4;   // 0..3

    // T1: bijective XCD swizzle (grids are multiples of 8)
    const int nwg = gridDim.x;
    const int cpx = nwg >> 3;
    int bid = blockIdx.x;
    bid = (bid & 7) * cpx + (bid >> 3);
    const int bx = bid % nbx, by = bid / nbx;
    const long row0 = (long)by * 256;
    const long col0 = (long)bx * 256;
    const int NT = K >> 6;

    // staging source (global pre-swizzled chunk, linear LDS dest; rule #21)
    const int tr = tid >> 3;                    // 0..63
    const int gc = (tid & 7) ^ (tr & 7);        // logical k-chunk for this slot
    const unsigned short* srcA = A + (row0 + tr) * (long)K + gc * 8;
    const unsigned short* srcB = Bt + (col0 + (tr >> 5) * 64 + (tr & 31)) * (long)K + gc * 8;

    // staged tile kt -> buf kt&1. A half h rows: i*128 + h*64 + tr (i=round).
    // B half h cols: i*128 + (tr>>5)*64 + h*32 + (tr&31).
    auto stageA = [&](int kt, int h) {
        const long ko = (long)kt * 64;
        unsigned short* dst = &lds[kt & 1][0][h][tid * 8];
        async_ld16(srcA + (h * 64) * (long)K + ko, dst);
        async_ld16(srcA + (128 + h * 64) * (long)K + ko, dst + 4096);
    };
    auto stageB = [&](int kt, int h) {
        const long ko = (long)kt * 64;
        unsigned short* dst = &lds[kt & 1][1][h][tid * 8];
        async_ld16(srcB + (h * 32) * (long)K + ko, dst);
        async_ld16(srcB + (128 + h * 32) * (long)K + ko, dst + 4096);
    };

    // read byte offsets within a half-buffer (idx&7 == lr&7 for all frags)
    int aoff[4][2], boff[2][2];
#pragma unroll
    for (int m = 0; m < 4; ++m)
#pragma unroll
        for (int ks = 0; ks < 2; ++ks)
            aoff[m][ks] = (wr * 64 + m * 16 + lr) * 128 + ((((ks * 4) | hi) ^ (lr & 7)) << 4);
#pragma unroll
    for (int n = 0; n < 2; ++n)
#pragma unroll
        for (int ks = 0; ks < 2; ++ks)
            boff[n][ks] = (wc * 32 + n * 16 + lr) * 128 + ((((ks * 4) | hi) ^ (lr & 7)) << 4);

    f32x4 acc[8][4];
#pragma unroll
    for (int i = 0; i < 8; ++i)
#pragma unroll
        for (int j = 0; j < 4; ++j) acc[i][j] = f32x4{0.f, 0.f, 0.f, 0.f};

    // prologue: tile 0, issue order A0,B0,B1,A1 (matches steady-state)
    stageA(0, 0); stageB(0, 0); stageB(0, 1); stageA(0, 1);

    bf16x8 a[4][2], b0[2][2], b1[2][2];

    for (int kt = 0; kt < NT; ++kt) {
        const int buf = kt & 1;
        const bool st = (kt + 1 < NT);
        const char* bA0 = (const char*)&lds[buf][0][0][0];
        const char* bA1 = (const char*)&lds[buf][0][1][0];
        const char* bB0 = (const char*)&lds[buf][1][0][0];
        const char* bB1 = (const char*)&lds[buf][1][1][0];

        // ---- p1: quadrant (m0,n0); needs A0(t),B0(t) ----
        asm volatile("s_waitcnt vmcnt(4)" ::: "memory");
        __builtin_amdgcn_s_barrier();
        __builtin_amdgcn_sched_barrier(0);
        if (st) stageA(kt + 1, 0);
#pragma unroll
        for (int n = 0; n < 2; ++n)
#pragma unroll
            for (int ks = 0; ks < 2; ++ks) b0[n][ks] = *(const bf16x8*)(bB0 + boff[n][ks]);
#pragma unroll
        for (int m = 0; m < 4; ++m)
#pragma unroll
            for (int ks = 0; ks < 2; ++ks) a[m][ks] = *(const bf16x8*)(bA0 + aoff[m][ks]);
        __builtin_amdgcn_s_setprio(1);
#pragma unroll
        for (int ks = 0; ks < 2; ++ks)
#pragma unroll
            for (int m = 0; m < 4; ++m)
#pragma unroll
                for (int n = 0; n < 2; ++n)
                    acc[m][n] = mfma16(a[m][ks], b0[n][ks], acc[m][n]);
        __builtin_amdgcn_s_setprio(0);

        // ---- p2: quadrant (m0,n1); needs B1(t); reuses a ----
        asm volatile("s_waitcnt vmcnt(4)" ::: "memory");
        __builtin_amdgcn_s_barrier();
        __builtin_amdgcn_sched_barrier(0);
        if (st) stageB(kt + 1, 0);
#pragma unroll
        for (int n = 0; n < 2; ++n)
#pragma unroll
            for (int ks = 0; ks < 2; ++ks) b1[n][ks] = *(const bf16x8*)(bB1 + boff[n][ks]);
        __builtin_amdgcn_s_setprio(1);
#pragma unroll
        for (int ks = 0; ks < 2; ++ks)
#pragma unroll
            for (int m = 0; m < 4; ++m)
#pragma unroll
                for (int n = 0; n < 2; ++n)
                    acc[m][2 + n] = mfma16(a[m][ks], b1[n][ks], acc[m][2 + n]);
        __builtin_amdgcn_s_setprio(0);

        // ---- p3: quadrant (m1,n0); needs A1(t); reuses b0 ----
        asm volatile("s_waitcnt vmcnt(4)" ::: "memory");
        __builtin_amdgcn_s_barrier();
        __builtin_amdgcn_sched_barrier(0);
        if (st) stageB(kt + 1, 1);
#pragma unroll
        for (int m = 0; m < 4; ++m)
#pragma unroll
            for (int ks = 0; ks < 2; ++ks) a[m][ks] = *(const bf16x8*)(bA1 + aoff[m][ks]);
        __builtin_amdgcn_s_setprio(1);
#pragma unroll
        for (int ks = 0; ks < 2; ++ks)
#pragma unroll
            for (int m = 0; m < 4; ++m)
#pragma unroll
                for (int n = 0; n < 2; ++n)
                    acc[4 + m][n] = mfma16(a[m][ks], b0[n][ks], acc[4 + m][n]);
        __builtin_amdgcn_s_setprio(0);

        // ---- p4: quadrant (m1,n1); all operands in regs; no wait/barrier ----
        if (st) stageA(kt + 1, 1);
        __builtin_amdgcn_s_setprio(1);
#pragma unroll
        for (int ks = 0; ks < 2; ++ks)
#pragma unroll
            for (int m = 0; m < 4; ++m)
#pragma unroll
                for (int n = 0; n < 2; ++n)
                    acc[4 + m][2 + n] = mfma16(a[m][ks], b1[n][ks], acc[4 + m][2 + n]);
        __builtin_amdgcn_s_setprio(0);
    }

    __syncthreads(); // drain: all K-loop LDS reads done before epilogue overwrite

    // acc[i][cn]: row = wr*128 + (i>>2)*64 + (i&3)*16 + hi*4 + j
    //             col = wc*64 + (cn>>1)*32 + (cn&1)*16 + lr
    float bcol[4];
#pragma unroll
    for (int cn = 0; cn < 4; ++cn)
        bcol[cn] = bias[col0 + wc * 64 + (cn >> 1) * 32 + (cn & 1) * 16 + lr];

    if (EPI == 2) {
        float (*eF)[256] = (float (*)[256])&lds[0][0][0][0]; // 128 x 256 f32
        float* co = (float*)Cout;
#pragma unroll
        for (int half = 0; half < 2; ++half) {
            if (wr == half) {
#pragma unroll
                for (int i = 0; i < 8; ++i)
#pragma unroll
                    for (int cn = 0; cn < 4; ++cn)
#pragma unroll
                        for (int j = 0; j < 4; ++j)
                            eF[(i >> 2) * 64 + (i & 3) * 16 + hi * 4 + j]
                              [wc * 64 + (cn >> 1) * 32 + (cn & 1) * 16 + lr] = acc[i][cn][j] + bcol[cn];
            }
            __syncthreads();
#pragma unroll
            for (int it = 0; it < 16; ++it) {
                const int idx = it * 512 + tid;
                const int row = idx >> 6;
                const int ch = (idx & 63) * 4;
                const long g = row0 + half * 128 + row;
                float4 v = *(const float4*)&eF[row][ch];
                const float4 rv = *(const float4*)&resid[g * N + col0 + ch];
                v.x += rv.x; v.y += rv.y; v.z += rv.z; v.w += rv.w;
                *(float4*)&co[g * N + col0 + ch] = v;
            }
            __syncthreads();
        }
    } else {
        unsigned short (*eT)[256] = (unsigned short (*)[256])&lds[0][0][0][0]; // 256x256 bf16
        unsigned short* co = (unsigned short*)Cout;
        const bool doRope = ROPE && (col0 + wc * 64) < 2048; // q,k cols only; wave-uniform
        if (doRope) {
#pragma unroll
            for (int i = 0; i < 8; ++i) {
                const int rbase = (i >> 2) * 64 + (i & 3) * 16;
                const float t_i = (float)(int)(((row0 + wr * 128 + rbase) >> 4) & 127);
#pragma unroll
                for (int cn = 0; cn < 2; ++cn) {
                    const float dd = (float)(cn * 16 + lr);
                    const float inv = __expf(dd * -0.2878231366242557f); // 10000^(-dd/32)
                    float sn, cs;
                    __sincosf(t_i * inv, &sn, &cs);
#pragma unroll
                    for (int j = 0; j < 4; ++j) {
                        const float lo = acc[i][cn][j] + bcol[cn];
                        const float hv = acc[i][cn + 2][j] + bcol[cn + 2];
                        eT[wr * 128 + rbase + hi * 4 + j][wc * 64 + cn * 16 + lr] = f2bf(lo * cs - hv * sn);
                        eT[wr * 128 + rbase + hi * 4 + j][wc * 64 + 32 + cn * 16 + lr] = f2bf(hv * cs + lo * sn);
                    }
                }
            }
        } else {
#pragma unroll
            for (int i = 0; i < 8; ++i)
#pragma unroll
                for (int cn = 0; cn < 4; ++cn)
#pragma unroll
                    for (int j = 0; j < 4; ++j) {
                        float v = acc[i][cn][j] + bcol[cn];
                        if (EPI == 1) v = gelu_f(v);
                        eT[wr * 128 + (i >> 2) * 64 + (i & 3) * 16 + hi * 4 + j]
                          [wc * 64 + (cn >> 1) * 32 + (cn & 1) * 16 + lr] = f2bf(v);
                    }
        }
        __syncthreads();
#pragma unroll
        for (int it = 0; it < 16; ++it) {
            const int idx = it * 512 + tid;
            const int row = idx >> 5;
            const int ch = (idx & 31) * 8;
            *(uint4*)&co[(row0 + row) * N + col0 + ch] = *(const uint4*)&eT[row][ch];
        }
    }
}

// ---------------- temporal attention: block per (b,m,h), S=128, causal -------
__global__ __launch_bounds__(256) void attn_temporal(
    const unsigned short* __restrict__ qkv, unsigned short* __restrict__ out)
{
    const int bid = blockIdx.x;
    const int h = bid & 15;
    const int mm = (bid >> 4) & 15;
    const int b = bid >> 8;
    const int tid = threadIdx.x;
    const int lane = tid & 63;
    const int wave = tid >> 6;
    const int lr = lane & 15;
    const int lk = (lane >> 4) * 8;
    const int r4 = (lane >> 4) * 4;

    __shared__ __align__(16) unsigned short smemA[128 * 136]; // Ks then aliased Ps
    __shared__ __align__(16) unsigned short smemV[64 * 136];
    unsigned short (*Ks)[72] = (unsigned short (*)[72])smemA;
    unsigned short (*Ps)[136] = (unsigned short (*)[136])smemA;
    unsigned short (*Vt)[136] = (unsigned short (*)[136])smemV;

    const long tokbase = (long)b * 2048 + mm; // token(t) = tokbase + 16*t

#pragma unroll
    for (int i = 0; i < 4; ++i) { // K tile: 128 x 64, 8-elem chunks
        const int cc = tid + 256 * i;
        const int s = cc >> 3, part = cc & 7;
        const unsigned short* g = qkv + (tokbase + s * 16l) * 3072 + 1024 + h * 64 + part * 8;
        *(uint4*)&Ks[s][part * 8] = *(const uint4*)g;
    }
#pragma unroll
    for (int i = 0; i < 4; ++i) { // V tile transposed into Vt[d][s]
        const int cc = tid + 256 * i;
        const int s = cc >> 3, part = cc & 7;
        const unsigned short* g = qkv + (tokbase + s * 16l) * 3072 + 2048 + h * 64 + part * 8;
        union { uint4 u; unsigned short us[8]; } uu;
        uu.u = *(const uint4*)g;
#pragma unroll
        for (int j = 0; j < 8; ++j) Vt[part * 8 + j][s] = uu.us[j];
    }
    __syncthreads();

    bf16x8 qf[2][2]; // Q frags direct from global
#pragma unroll
    for (int rb = 0; rb < 2; ++rb)
#pragma unroll
        for (int ks = 0; ks < 2; ++ks) {
            const int t = wave * 32 + rb * 16 + lr;
            qf[rb][ks] = *(const bf16x8*)(qkv + (tokbase + t * 16l) * 3072 + h * 64 + ks * 32 + lk);
        }

    f32x4 sacc[2][8];
#pragma unroll
    for (int rb = 0; rb < 2; ++rb)
#pragma unroll
        for (int cb = 0; cb < 8; ++cb) sacc[rb][cb] = f32x4{0.f, 0.f, 0.f, 0.f};

#pragma unroll
    for (int cb = 0; cb < 8; ++cb)
#pragma unroll
        for (int ks = 0; ks < 2; ++ks) {
            const bf16x8 kf = *(const bf16x8*)&Ks[cb * 16 + lr][ks * 32 + lk];
            sacc[0][cb] = mfma16(qf[0][ks], kf, sacc[0][cb]);
            sacc[1][cb] = mfma16(qf[1][ks], kf, sacc[1][cb]);
        }

    float recip[2][4];
#pragma unroll
    for (int rb = 0; rb < 2; ++rb)
#pragma unroll
        for (int r = 0; r < 4; ++r) {
            const int trow = wave * 32 + rb * 16 + r4 + r;
            float mx = -1e30f;
#pragma unroll
            for (int cb = 0; cb < 8; ++cb) {
                const int s = cb * 16 + lr;
                const float v = (s <= trow) ? sacc[rb][cb][r] * 0.125f : -1e30f;
                sacc[rb][cb][r] = v;
                mx = fmaxf(mx, v);
            }
            mx = fmaxf(mx, __shfl_xor(mx, 1));
            mx = fmaxf(mx, __shfl_xor(mx, 2));
            mx = fmaxf(mx, __shfl_xor(mx, 4));
            mx = fmaxf(mx, __shfl_xor(mx, 8));
            float sum = 0.f;
#pragma unroll
            for (int cb = 0; cb < 8; ++cb) {
                const float e = __expf(sacc[rb][cb][r] - mx);
                sacc[rb][cb][r] = e;
                sum += e;
            }
            sum += __shfl_xor(sum, 1);
            sum += __shfl_xor(sum, 2);
            sum += __shfl_xor(sum, 4);
            sum += __shfl_xor(sum, 8);
            recip[rb][r] = 1.f / sum;
        }
    __syncthreads(); // all waves done reading Ks before overwriting with Ps

#pragma unroll
    for (int rb = 0; rb < 2; ++rb)
#pragma unroll
        for (int cb = 0; cb < 8; ++cb)
#pragma unroll
            for (int r = 0; r < 4; ++r)
                Ps[wave * 32 + rb * 16 + r4 + r][cb * 16 + lr] = f2bf(sacc[rb][cb][r]);
    __syncthreads();

    f32x4 oacc[2][4];
#pragma unroll
    for (int rb = 0; rb < 2; ++rb)
#pragma unroll
        for (int cb = 0; cb < 4; ++cb) oacc[rb][cb] = f32x4{0.f, 0.f, 0.f, 0.f};

#pragma unroll
    for (int ks = 0; ks < 4; ++ks) {
        bf16x8 pf[2];
        pf[0] = *(const bf16x8*)&Ps[wave * 32 + lr][ks * 32 + lk];
        pf[1] = *(const bf16x8*)&Ps[wave * 32 + 16 + lr][ks * 32 + lk];
#pragma unroll
        for (int cb = 0; cb < 4; ++cb) {
            const bf16x8 vf = *(const bf16x8*)&Vt[cb * 16 + lr][ks * 32 + lk];
            oacc[0][cb] = mfma16(pf[0], vf, oacc[0][cb]);
            oacc[1][cb] = mfma16(pf[1], vf, oacc[1][cb]);
        }
    }

#pragma unroll
    for (int rb = 0; rb < 2; ++rb)
#pragma unroll
        for (int cb = 0; cb < 4; ++cb)
#pragma unroll
            for (int r = 0; r < 4; ++r) {
                const int trow = wave * 32 + rb * 16 + r4 + r;
                out[(tokbase + trow * 16l) * 1024 + h * 64 + cb * 16 + lr] =
                    f2bf(oacc[rb][cb][r] * recip[rb][r]);
            }
}

// ---------------- modality attention: block per (b,t), S=16, 4 heads/wave ----
__global__ __launch_bounds__(256) void attn_modality(
    const unsigned short* __restrict__ qkv, unsigned short* __restrict__ out)
{
    const int tid = threadIdx.x;
    const int lane = tid & 63;
    const int wave = tid >> 6;
    const int lr = lane & 15;
    const int lk = (lane >> 4) * 8;
    const int r4 = (lane >> 4) * 4;
    const long base = (long)blockIdx.x * 16;

    __shared__ __align__(16) unsigned short smem[4][64 * 40 + 16 * 40]; // per-wave Vt + P
    unsigned short (*Vt)[40] = (unsigned short (*)[40]) & smem[wave][0];
    unsigned short (*Pl)[40] = (unsigned short (*)[40]) & smem[wave][64 * 40];

    // zero whole per-wave region once (zero-padding for K=16 -> 32)
    for (int i = lane; i < 400; i += 64)
        *(uint4*)&smem[wave][i * 8] = make_uint4(0u, 0u, 0u, 0u);

    for (int hi = 0; hi < 4; ++hi) {
        const int h = wave * 4 + hi;
#pragma unroll
        for (int i = 0; i < 2; ++i) { // V head tile 16x64 transposed
            const int cc = lane + 64 * i;
            const int s = cc >> 3, d0 = (cc & 7) * 8;
            union { uint4 u; unsigned short us[8]; } uu;
            uu.u = *(const uint4*)(qkv + (base + s) * 3072 + 2048 + h * 64 + d0);
#pragma unroll
            for (int j = 0; j < 8; ++j) Vt[d0 + j][s] = uu.us[j];
        }
        bf16x8 qf[2], kf[2];
#pragma unroll
        for (int ks = 0; ks < 2; ++ks) {
            qf[ks] = *(const bf16x8*)(qkv + (base + lr) * 3072 + h * 64 + ks * 32 + lk);
            kf[ks] = *(const bf16x8*)(qkv + (base + lr) * 3072 + 1024 + h * 64 + ks * 32 + lk);
        }
        f32x4 sv = f32x4{0.f, 0.f, 0.f, 0.f};
        sv = mfma16(qf[0], kf[0], sv);
        sv = mfma16(qf[1], kf[1], sv);

        float recip[4], pe[4];
#pragma unroll
        for (int r = 0; r < 4; ++r) {
            const float v = sv[r] * 0.125f;
            float mx = v;
            mx = fmaxf(mx, __shfl_xor(mx, 1));
            mx = fmaxf(mx, __shfl_xor(mx, 2));
            mx = fmaxf(mx, __shfl_xor(mx, 4));
            mx = fmaxf(mx, __shfl_xor(mx, 8));
            const float e = __expf(v - mx);
            float sum = e;
            sum += __shfl_xor(sum, 1);
            sum += __shfl_xor(sum, 2);
            sum += __shfl_xor(sum, 4);
            sum += __shfl_xor(sum, 8);
            recip[r] = 1.f / sum;
            pe[r] = e;
        }
#pragma unroll
        for (int r = 0; r < 4; ++r) Pl[r4 + r][lr] = f2bf(pe[r]);

        const bf16x8 pf = *(const bf16x8*)&Pl[lr][lk];
#pragma unroll
        for (int cb = 0; cb < 4; ++cb) {
            const bf16x8 vf = *(const bf16x8*)&Vt[cb * 16 + lr][lk];
            f32x4 o = f32x4{0.f, 0.f, 0.f, 0.f};
            o = mfma16(pf, vf, o);
#pragma unroll
            for (int r = 0; r < 4; ++r)
                out[(base + r4 + r) * 1024 + h * 64 + cb * 16 + lr] = f2bf(o[r] * recip[r]);
        }
    }
}

// -----------------------------------------------------------------------------
extern "C" void kernel_launch(void* const* d_in, const int* in_sizes, int n_in,
                              void* d_out, int out_size, void* d_ws, size_t ws_size,
                              hipStream_t stream)
{
    (void)in_sizes; (void)n_in; (void)out_size;
    const float* x    = (const float*)d_in[0];
    const float* ln1s = (const float*)d_in[1];
    const float* ln1b = (const float*)d_in[2];
    const float* tWq  = (const float*)d_in[3];
    const float* tbq  = (const float*)d_in[4];
    const float* tWk  = (const float*)d_in[5];
    const float* tbk  = (const float*)d_in[6];
    const float* tWv  = (const float*)d_in[7];
    const float* tbv  = (const float*)d_in[8];
    const float* tWo  = (const float*)d_in[9];
    const float* tbo  = (const float*)d_in[10];
    const float* ln2s = (const float*)d_in[11];
    const float* ln2b = (const float*)d_in[12];
    const float* mWq  = (const float*)d_in[13];
    const float* mbq  = (const float*)d_in[14];
    const float* mWk  = (const float*)d_in[15];
    const float* mbk  = (const float*)d_in[16];
    const float* mWv  = (const float*)d_in[17];
    const float* mbv  = (const float*)d_in[18];
    const float* mWo  = (const float*)d_in[19];
    const float* mbo  = (const float*)d_in[20];
    const float* ln3s = (const float*)d_in[21];
    const float* ln3b = (const float*)d_in[22];
    const float* W1   = (const float*)d_in[23];
    const float* b1   = (const float*)d_in[24];
    const float* W2   = (const float*)d_in[25];
    const float* b2   = (const float*)d_in[26];

    if (ws_size < 201351168ull) return; // need ~192 MiB scratch

    char* ws = (char*)d_ws;
    unsigned short* Wt_tqkv = (unsigned short*)(ws + 0);
    unsigned short* Wt_to   = (unsigned short*)(ws + 6291456);
    unsigned short* Wt_mqkv = (unsigned short*)(ws + 8388608);
    unsigned short* Wt_mo   = (unsigned short*)(ws + 14680064);
    unsigned short* Wt1     = (unsigned short*)(ws + 16777216);
    unsigned short* Wt2     = (unsigned short*)(ws + 25165824);
    float* bias_t           = (float*)(ws + 33554432);
    float* bias_m           = (float*)(ws + 33566720);
    unsigned short* act     = (unsigned short*)(ws + 33579008); // LN out / attn out (33.5MB)
    unsigned short* qkv     = (unsigned short*)(ws + 67133440); // 100.7MB, reused as MLP hidden
    unsigned short* hidden  = qkv;
    float* xout = (float*)d_out; // fp32 residual stream lives in d_out

    dim3 blk(256);
    dim3 blk5(512);

    // weight conversion (per call; deterministic)
    wconv_kernel<<<dim3(32, 32), blk, 0, stream>>>(tWq, Wt_tqkv, 1024, 1024);
    wconv_kernel<<<dim3(32, 32), blk, 0, stream>>>(tWk, Wt_tqkv + 1024 * 1024, 1024, 1024);
    wconv_kernel<<<dim3(32, 32), blk, 0, stream>>>(tWv, Wt_tqkv + 2048 * 1024, 1024, 1024);
    wconv_kernel<<<dim3(32, 32), blk, 0, stream>>>(tWo, Wt_to, 1024, 1024);
    wconv_kernel<<<dim3(32, 32), blk, 0, stream>>>(mWq, Wt_mqkv, 1024, 1024);
    wconv_kernel<<<dim3(32, 32), blk, 0, stream>>>(mWk, Wt_mqkv + 1024 * 1024, 1024, 1024);
    wconv_kernel<<<dim3(32, 32), blk, 0, stream>>>(mWv, Wt_mqkv + 2048 * 1024, 1024, 1024);
    wconv_kernel<<<dim3(32, 32), blk, 0, stream>>>(mWo, Wt_mo, 1024, 1024);
    wconv_kernel<<<dim3(128, 32), blk, 0, stream>>>(W1, Wt1, 1024, 4096);
    wconv_kernel<<<dim3(32, 128), blk, 0, stream>>>(W2, Wt2, 4096, 1024);
    pack_bias_kernel<<<12, blk, 0, stream>>>(tbq, tbk, tbv, bias_t);
    pack_bias_kernel<<<12, blk, 0, stream>>>(mbq, mbk, mbv, bias_m);

    // 1. LN1
    ln_kernel<<<4096, blk, 0, stream>>>(x, ln1s, ln1b, act);
    // 2. temporal QKV + fused RoPE  (M=16384, N=3072, K=1024) -> grid 64*12=768
    gemm256_kernel<0, true><<<768, blk5, 0, stream>>>(act, Wt_tqkv, bias_t, nullptr, qkv, 16384, 3072, 1024, 12);
    // 3. temporal attention (causal over T=128)
    attn_temporal<<<2048, blk, 0, stream>>>(qkv, act);
    // 4. out-proj + residual(x) -> xout (fp32)   N=1024 -> grid 64*4=256
    gemm256_kernel<2, false><<<256, blk5, 0, stream>>>(act, Wt_to, tbo, x, xout, 16384, 1024, 1024, 4);
    // 5. LN2
    ln_kernel<<<4096, blk, 0, stream>>>(xout, ln2s, ln2b, act);
    // 6. modality QKV
    gemm256_kernel<0, false><<<768, blk5, 0, stream>>>(act, Wt_mqkv, bias_m, nullptr, qkv, 16384, 3072, 1024, 12);
    // 7. modality attention (S=16, no mask, no rope)
    attn_modality<<<1024, blk, 0, stream>>>(qkv, act);
    // 8. out-proj + residual -> xout
    gemm256_kernel<2, false><<<256, blk5, 0, stream>>>(act, Wt_mo, mbo, xout, xout, 16384, 1024, 1024, 4);
    // 9. LN3
    ln_kernel<<<4096, blk, 0, stream>>>(xout, ln3s, ln3b, act);
    // 10. MLP up + GELU  (N=4096) -> grid 64*16=1024
    gemm256_kernel<1, false><<<1024, blk5, 0, stream>>>(act, Wt1, b1, nullptr, hidden, 16384, 4096, 1024, 16);
    // 11. MLP down + residual -> xout  (K=4096)
    gemm256_kernel<2, false><<<256, blk5, 0, stream>>>(hidden, Wt2, b2, xout, xout, 16384, 1024, 4096, 4);
}